// Round 1
// baseline (1699.049 us; speedup 1.0000x reference)
//
#include <hip/hip_runtime.h>

#define NN 30000
#define EE 300000
#define FF 128
#define HH 4
#define DD 32
#define CC 16
#define SLOPE 0.2f

// ---------------- GEMM: out[n][m] = sum_k A[n][k] * W[k][m]  (K=M=128) ----------------
// block = 256 threads = 32 rows x 8 colgroups (16 cols each); A tile staged in LDS.
__global__ __launch_bounds__(256) void gemm128(const float* __restrict__ A,
                                               const float* __restrict__ W,
                                               float* __restrict__ out) {
    __shared__ float At[32][132];  // +4 pad: banks (r*132+k)%32 = (4r+k)%32, conflict-free
    const int row0 = blockIdx.x * 32;
    const int t = threadIdx.x;
    for (int i = t; i < 32 * 32; i += 256) {
        const int r = i >> 5, c4 = i & 31;
        const int row = row0 + r;
        float4 v = make_float4(0.f, 0.f, 0.f, 0.f);
        if (row < NN) v = reinterpret_cast<const float4*>(A)[row * 32 + c4];
        *reinterpret_cast<float4*>(&At[r][c4 * 4]) = v;
    }
    __syncthreads();
    const int r = t >> 3;          // 0..31
    const int cg = t & 7;          // 0..7 -> cols cg*16 .. cg*16+15
    const int row = row0 + r;
    float4 a0 = {0,0,0,0}, a1 = {0,0,0,0}, a2 = {0,0,0,0}, a3 = {0,0,0,0};
    const float4* Wv = reinterpret_cast<const float4*>(W) + cg * 4;
    #pragma unroll 4
    for (int k = 0; k < 128; ++k) {
        const float a = At[r][k];
        const float4 w0 = Wv[k * 32 + 0];
        const float4 w1 = Wv[k * 32 + 1];
        const float4 w2 = Wv[k * 32 + 2];
        const float4 w3 = Wv[k * 32 + 3];
        a0.x = fmaf(a, w0.x, a0.x); a0.y = fmaf(a, w0.y, a0.y);
        a0.z = fmaf(a, w0.z, a0.z); a0.w = fmaf(a, w0.w, a0.w);
        a1.x = fmaf(a, w1.x, a1.x); a1.y = fmaf(a, w1.y, a1.y);
        a1.z = fmaf(a, w1.z, a1.z); a1.w = fmaf(a, w1.w, a1.w);
        a2.x = fmaf(a, w2.x, a2.x); a2.y = fmaf(a, w2.y, a2.y);
        a2.z = fmaf(a, w2.z, a2.z); a2.w = fmaf(a, w2.w, a2.w);
        a3.x = fmaf(a, w3.x, a3.x); a3.y = fmaf(a, w3.y, a3.y);
        a3.z = fmaf(a, w3.z, a3.z); a3.w = fmaf(a, w3.w, a3.w);
    }
    if (row < NN) {
        float4* o = reinterpret_cast<float4*>(out + row * 128) + cg * 4;
        o[0] = a0; o[1] = a1; o[2] = a2; o[3] = a3;
    }
}

// ---------------- el/er: per (node, head) dot of feat[n,h,:] with al/ar[h,:] ----------------
__global__ __launch_bounds__(256) void eler_k(const float* __restrict__ feat,
                                              const float* __restrict__ al,
                                              const float* __restrict__ ar,
                                              float* __restrict__ el,
                                              float* __restrict__ er) {
    const int gid = blockIdx.x * 256 + threadIdx.x;   // n*HH + h
    if (gid >= NN * HH) return;
    const int n = gid >> 2, h = gid & 3;
    const float4* f = reinterpret_cast<const float4*>(feat + n * 128 + h * 32);
    const float4* a = reinterpret_cast<const float4*>(al + h * 32);
    const float4* b = reinterpret_cast<const float4*>(ar + h * 32);
    float sl = 0.f, sr = 0.f;
    #pragma unroll
    for (int j = 0; j < 8; ++j) {
        const float4 fv = f[j], av = a[j], bv = b[j];
        sl += fv.x * av.x + fv.y * av.y + fv.z * av.z + fv.w * av.w;
        sr += fv.x * bv.x + fv.y * bv.y + fv.z * bv.z + fv.w * bv.w;
    }
    el[gid] = sl;
    er[gid] = sr;
}

// ---------------- edge pass 1: ex = exp(leaky(el[src]+er[dst])); s[dst] += ex ----------------
// (segment-max subtraction dropped: mathematically identical, |e| is O(5) here)
__global__ __launch_bounds__(256) void edge_exp_k(const int* __restrict__ src,
                                                  const int* __restrict__ dst,
                                                  const float* __restrict__ el,
                                                  const float* __restrict__ er,
                                                  float* __restrict__ ex,
                                                  float* __restrict__ s) {
    const int gid = blockIdx.x * 256 + threadIdx.x;   // e*HH + h
    if (gid >= EE * HH) return;
    const int e = gid >> 2, h = gid & 3;
    const int si = src[e], di = dst[e];
    float v = el[si * 4 + h] + er[di * 4 + h];
    v = (v >= 0.f) ? v : v * SLOPE;
    const float xv = __expf(v);
    ex[gid] = xv;
    atomicAdd(&s[di * 4 + h], xv);
}

// ---------------- invert softmax denominators (isolated nodes -> inf, never read) ----------------
__global__ __launch_bounds__(256) void sinv_k(float* __restrict__ s, int n) {
    const int gid = blockIdx.x * 256 + threadIdx.x;
    if (gid < n) s[gid] = 1.f / s[gid];
}

// ---------------- edge pass 2: acc[dst, c] += alpha * feat[src, c] ----------------
__global__ __launch_bounds__(256) void aggregate_k(const int* __restrict__ src,
                                                   const int* __restrict__ dst,
                                                   const float* __restrict__ ex,
                                                   const float* __restrict__ sinv,
                                                   const float* __restrict__ feat,
                                                   float* __restrict__ acc) {
    const int gid = blockIdx.x * 256 + threadIdx.x;   // e*128 + c  (EE*128 exact)
    const int e = gid >> 7, c = gid & 127, h = c >> 5;
    const int si = src[e], di = dst[e];
    const float alpha = ex[e * 4 + h] * sinv[di * 4 + h];
    atomicAdd(&acc[di * 128 + c], alpha * feat[si * 128 + c]);
}

// ---------------- bias (sum over etypes) + optional relu ----------------
__global__ __launch_bounds__(256) void finish_k(const float* __restrict__ acc,
                                                const float* __restrict__ b0,
                                                const float* __restrict__ b1,
                                                float* __restrict__ out, int relu) {
    const int gid = blockIdx.x * 256 + threadIdx.x;   // NN*128 exact
    const int c = gid & 127;
    float v = acc[gid] + b0[c] + b1[c];
    if (relu) v = fmaxf(v, 0.f);
    out[gid] = v;
}

// ---------------- final linear: out[n][c] = sum_k h[n][k]*Wout[k][c] + bout[c] ----------------
__global__ __launch_bounds__(256) void out_gemm_k(const float* __restrict__ A,
                                                  const float* __restrict__ W,
                                                  const float* __restrict__ bout,
                                                  float* __restrict__ out) {
    __shared__ float At[16][132];
    const int row0 = blockIdx.x * 16;   // NN % 16 == 0
    const int t = threadIdx.x;
    for (int i = t; i < 16 * 32; i += 256) {
        const int r = i >> 5, c4 = i & 31;
        *reinterpret_cast<float4*>(&At[r][c4 * 4]) =
            reinterpret_cast<const float4*>(A)[(row0 + r) * 32 + c4];
    }
    __syncthreads();
    const int r = t >> 4, c = t & 15;
    float accv = 0.f;
    #pragma unroll 8
    for (int k = 0; k < 128; ++k) accv = fmaf(At[r][k], W[k * 16 + c], accv);
    out[(row0 + r) * 16 + c] = accv + bout[c];
}

extern "C" void kernel_launch(void* const* d_in, const int* in_sizes, int n_in,
                              void* d_out, int out_size, void* d_ws, size_t ws_size,
                              hipStream_t stream) {
    (void)in_sizes; (void)n_in; (void)out_size; (void)ws_size;
    const float* x = (const float*)d_in[0];
    const int* src[2] = {(const int*)d_in[1], (const int*)d_in[3]};
    const int* dst[2] = {(const int*)d_in[2], (const int*)d_in[4]};
    const float* W[3]  = {(const float*)d_in[5], (const float*)d_in[9],  (const float*)d_in[13]};
    const float* al[3] = {(const float*)d_in[6], (const float*)d_in[10], (const float*)d_in[14]};
    const float* ar[3] = {(const float*)d_in[7], (const float*)d_in[11], (const float*)d_in[15]};
    const float* bb[3] = {(const float*)d_in[8], (const float*)d_in[12], (const float*)d_in[16]};
    const float* Wout = (const float*)d_in[17];
    const float* bout = (const float*)d_in[18];
    float* outp = (float*)d_out;

    float* p = (float*)d_ws;
    float* feat[2] = {p, p + NN * 128};          p += 2 * NN * 128;
    float* el[2]   = {p, p + NN * HH};           p += 2 * NN * HH;
    float* er[2]   = {p, p + NN * HH};           p += 2 * NN * HH;
    float* sv[2]   = {p, p + NN * HH};           p += 2 * NN * HH;   // sv[0],sv[1] contiguous
    float* ex[2]   = {p, p + EE * HH};           p += 2 * EE * HH;
    float* acc     = p;                          p += NN * 128;
    float* hbuf    = p;                          p += NN * 128;
    // total ws use: ~18.5M floats = 74 MB

    const float* hin = x;
    for (int l = 0; l < 3; ++l) {
        for (int t = 0; t < 2; ++t)
            gemm128<<<(NN + 31) / 32, 256, 0, stream>>>(hin, W[l] + t * 128 * 128, feat[t]);
        for (int t = 0; t < 2; ++t)
            eler_k<<<(NN * HH + 255) / 256, 256, 0, stream>>>(feat[t], al[l] + t * 128,
                                                              ar[l] + t * 128, el[t], er[t]);
        hipMemsetAsync(sv[0], 0, 2 * NN * HH * sizeof(float), stream);
        hipMemsetAsync(acc, 0, (size_t)NN * 128 * sizeof(float), stream);
        for (int t = 0; t < 2; ++t)
            edge_exp_k<<<(EE * HH + 255) / 256, 256, 0, stream>>>(src[t], dst[t], el[t], er[t],
                                                                  ex[t], sv[t]);
        sinv_k<<<(2 * NN * HH + 255) / 256, 256, 0, stream>>>(sv[0], 2 * NN * HH);
        for (int t = 0; t < 2; ++t)
            aggregate_k<<<EE * 128 / 256, 256, 0, stream>>>(src[t], dst[t], ex[t], sv[t],
                                                            feat[t], acc);
        finish_k<<<NN * 128 / 256, 256, 0, stream>>>(acc, bb[l], bb[l] + 128, hbuf,
                                                     (l < 2) ? 1 : 0);
        hin = hbuf;
    }
    out_gemm_k<<<NN / 16, 256, 0, stream>>>(hbuf, Wout, bout, outp);
}

// Round 2
// 1171.257 us; speedup vs baseline: 1.4506x; 1.4506x over previous
//
#include <hip/hip_runtime.h>

#define NN 30000
#define EE 300000
#define HH 4
#define SLOPE 0.2f

// ---------------- GEMM: out[n][m] = sum_k A[n][k] * W[k][m]  (K=M=128), grid.y = etype ----------------
__global__ __launch_bounds__(256) void gemm128(const float* __restrict__ A,
                                               const float* __restrict__ Wbase,
                                               float* __restrict__ outbase) {
    __shared__ float At[32][132];
    const float* W = Wbase + blockIdx.y * 128 * 128;
    float* out = outbase + (size_t)blockIdx.y * NN * 128;
    const int row0 = blockIdx.x * 32;
    const int t = threadIdx.x;
    for (int i = t; i < 32 * 32; i += 256) {
        const int r = i >> 5, c4 = i & 31;
        const int row = row0 + r;
        float4 v = make_float4(0.f, 0.f, 0.f, 0.f);
        if (row < NN) v = reinterpret_cast<const float4*>(A)[row * 32 + c4];
        *reinterpret_cast<float4*>(&At[r][c4 * 4]) = v;
    }
    __syncthreads();
    const int r = t >> 3;
    const int cg = t & 7;
    const int row = row0 + r;
    float4 a0 = {0,0,0,0}, a1 = {0,0,0,0}, a2 = {0,0,0,0}, a3 = {0,0,0,0};
    const float4* Wv = reinterpret_cast<const float4*>(W) + cg * 4;
    #pragma unroll 4
    for (int k = 0; k < 128; ++k) {
        const float a = At[r][k];
        const float4 w0 = Wv[k * 32 + 0];
        const float4 w1 = Wv[k * 32 + 1];
        const float4 w2 = Wv[k * 32 + 2];
        const float4 w3 = Wv[k * 32 + 3];
        a0.x = fmaf(a, w0.x, a0.x); a0.y = fmaf(a, w0.y, a0.y);
        a0.z = fmaf(a, w0.z, a0.z); a0.w = fmaf(a, w0.w, a0.w);
        a1.x = fmaf(a, w1.x, a1.x); a1.y = fmaf(a, w1.y, a1.y);
        a1.z = fmaf(a, w1.z, a1.z); a1.w = fmaf(a, w1.w, a1.w);
        a2.x = fmaf(a, w2.x, a2.x); a2.y = fmaf(a, w2.y, a2.y);
        a2.z = fmaf(a, w2.z, a2.z); a2.w = fmaf(a, w2.w, a2.w);
        a3.x = fmaf(a, w3.x, a3.x); a3.y = fmaf(a, w3.y, a3.y);
        a3.z = fmaf(a, w3.z, a3.z); a3.w = fmaf(a, w3.w, a3.w);
    }
    if (row < NN) {
        float4* o = reinterpret_cast<float4*>(out + (size_t)row * 128) + cg * 4;
        o[0] = a0; o[1] = a1; o[2] = a2; o[3] = a3;
    }
}

// ---------------- el/er per (node, head); grid.y = etype ----------------
__global__ __launch_bounds__(256) void eler_k(const float* __restrict__ featbase,
                                              const float* __restrict__ albase,
                                              const float* __restrict__ arbase,
                                              float* __restrict__ elbase,
                                              float* __restrict__ erbase) {
    const int gid = blockIdx.x * 256 + threadIdx.x;   // n*HH + h
    if (gid >= NN * HH) return;
    const int t = blockIdx.y;
    const float* feat = featbase + (size_t)t * NN * 128;
    const float* al = albase + t * 128;
    const float* ar = arbase + t * 128;
    const int n = gid >> 2, h = gid & 3;
    const float4* f = reinterpret_cast<const float4*>(feat + n * 128 + h * 32);
    const float4* a = reinterpret_cast<const float4*>(al + h * 32);
    const float4* b = reinterpret_cast<const float4*>(ar + h * 32);
    float sl = 0.f, sr = 0.f;
    #pragma unroll
    for (int j = 0; j < 8; ++j) {
        const float4 fv = f[j], av = a[j], bv = b[j];
        sl += fv.x * av.x + fv.y * av.y + fv.z * av.z + fv.w * av.w;
        sr += fv.x * bv.x + fv.y * bv.y + fv.z * bv.z + fv.w * bv.w;
    }
    (elbase + t * NN * HH)[gid] = sl;
    (erbase + t * NN * HH)[gid] = sr;
}

// ---------------- CSR build: histogram (grid.y = etype) ----------------
__global__ __launch_bounds__(256) void hist_k(const int* __restrict__ dst0,
                                              const int* __restrict__ dst1,
                                              int* __restrict__ deg) {
    const int e = blockIdx.x * 256 + threadIdx.x;
    if (e >= EE) return;
    const int t = blockIdx.y;
    const int* d = t ? dst1 : dst0;
    atomicAdd(&deg[t * NN + d[e]], 1);
}

// ---------------- CSR build: exclusive scan, one block per etype ----------------
__global__ __launch_bounds__(256) void scan_k(const int* __restrict__ deg,
                                              int* __restrict__ offs,
                                              int* __restrict__ cursor) {
    const int t = blockIdx.x;
    const int* d = deg + t * NN;
    int* o = offs + t * (NN + 1);
    int* cur = cursor + t * NN;
    __shared__ int buf[256];
    __shared__ int carry;
    if (threadIdx.x == 0) carry = 0;
    __syncthreads();
    for (int base = 0; base < NN; base += 256) {
        const int i = base + threadIdx.x;
        const int v = (i < NN) ? d[i] : 0;
        buf[threadIdx.x] = v;
        __syncthreads();
        #pragma unroll
        for (int ofs = 1; ofs < 256; ofs <<= 1) {
            const int add = (threadIdx.x >= (unsigned)ofs) ? buf[threadIdx.x - ofs] : 0;
            __syncthreads();
            buf[threadIdx.x] += add;
            __syncthreads();
        }
        const int inc = buf[threadIdx.x];
        const int exc = carry + inc - v;
        if (i < NN) { o[i] = exc; cur[i] = exc; }
        __syncthreads();
        if (threadIdx.x == 255) carry += inc;
        __syncthreads();
    }
    if (threadIdx.x == 0) o[NN] = carry;
}

// ---------------- CSR build: scatter src into dst-sorted order (grid.y = etype) ----------------
__global__ __launch_bounds__(256) void scatter_k(const int* __restrict__ src0,
                                                 const int* __restrict__ dst0,
                                                 const int* __restrict__ src1,
                                                 const int* __restrict__ dst1,
                                                 int* __restrict__ cursor,
                                                 int* __restrict__ csr_src) {
    const int e = blockIdx.x * 256 + threadIdx.x;
    if (e >= EE) return;
    const int t = blockIdx.y;
    const int* s = t ? src1 : src0;
    const int* d = t ? dst1 : dst0;
    const int pos = atomicAdd(&cursor[t * NN + d[e]], 1);
    csr_src[t * EE + pos] = s[e];
}

// ---------------- pull-mode fused softmax+aggregate+bias(+relu): one wave per node ----------------
__global__ __launch_bounds__(256) void pull_agg_k(const int* __restrict__ csr_src,
                                                  const int* __restrict__ offs,
                                                  const float* __restrict__ el,
                                                  const float* __restrict__ er,
                                                  const float* __restrict__ feat,
                                                  const float* __restrict__ b0,
                                                  const float* __restrict__ b1,
                                                  float* __restrict__ out, int relu) {
    const int wave = (blockIdx.x * 256 + threadIdx.x) >> 6;
    const int lane = threadIdx.x & 63;
    if (wave >= NN) return;
    const int n = wave;
    const int c0 = lane * 2;        // this lane owns cols c0, c0+1
    const int h = c0 >> 5;          // head for both cols
    float a0 = 0.f, a1 = 0.f;
    #pragma unroll
    for (int t = 0; t < 2; ++t) {
        const int* so = offs + t * (NN + 1);
        const int e0 = so[n], e1 = so[n + 1];
        const float erh = er[t * NN * HH + n * HH + h];
        const int* cs = csr_src + t * EE;
        const float* ft = feat + (size_t)t * NN * 128;
        const float* elt = el + t * NN * HH;
        float s = 0.f, x0 = 0.f, x1 = 0.f;
        for (int e = e0; e < e1; ++e) {
            const int sidx = cs[e];
            float v = elt[sidx * HH + h] + erh;
            v = (v >= 0.f) ? v : v * SLOPE;
            const float ex = __expf(v);
            s += ex;
            const float2 fr = *reinterpret_cast<const float2*>(ft + (size_t)sidx * 128 + c0);
            x0 = fmaf(ex, fr.x, x0);
            x1 = fmaf(ex, fr.y, x1);
        }
        const float inv = (s > 0.f) ? 1.f / s : 0.f;   // isolated node -> 0, matches ref
        a0 = fmaf(x0, inv, a0);
        a1 = fmaf(x1, inv, a1);
    }
    a0 += b0[c0] + b1[c0];
    a1 += b0[c0 + 1] + b1[c0 + 1];
    if (relu) { a0 = fmaxf(a0, 0.f); a1 = fmaxf(a1, 0.f); }
    *reinterpret_cast<float2*>(out + (size_t)n * 128 + c0) = make_float2(a0, a1);
}

// ---------------- final linear ----------------
__global__ __launch_bounds__(256) void out_gemm_k(const float* __restrict__ A,
                                                  const float* __restrict__ W,
                                                  const float* __restrict__ bout,
                                                  float* __restrict__ out) {
    __shared__ float At[16][132];
    const int row0 = blockIdx.x * 16;
    const int t = threadIdx.x;
    for (int i = t; i < 16 * 32; i += 256) {
        const int r = i >> 5, c4 = i & 31;
        *reinterpret_cast<float4*>(&At[r][c4 * 4]) =
            reinterpret_cast<const float4*>(A)[(row0 + r) * 32 + c4];
    }
    __syncthreads();
    const int r = t >> 4, c = t & 15;
    float accv = 0.f;
    #pragma unroll 8
    for (int k = 0; k < 128; ++k) accv = fmaf(At[r][k], W[k * 16 + c], accv);
    out[(row0 + r) * 16 + c] = accv + bout[c];
}

extern "C" void kernel_launch(void* const* d_in, const int* in_sizes, int n_in,
                              void* d_out, int out_size, void* d_ws, size_t ws_size,
                              hipStream_t stream) {
    (void)in_sizes; (void)n_in; (void)out_size; (void)ws_size;
    const float* x = (const float*)d_in[0];
    const int* src0 = (const int*)d_in[1];
    const int* dst0 = (const int*)d_in[2];
    const int* src1 = (const int*)d_in[3];
    const int* dst1 = (const int*)d_in[4];
    const float* W[3]  = {(const float*)d_in[5], (const float*)d_in[9],  (const float*)d_in[13]};
    const float* al[3] = {(const float*)d_in[6], (const float*)d_in[10], (const float*)d_in[14]};
    const float* ar[3] = {(const float*)d_in[7], (const float*)d_in[11], (const float*)d_in[15]};
    const float* bb[3] = {(const float*)d_in[8], (const float*)d_in[12], (const float*)d_in[16]};
    const float* Wout = (const float*)d_in[17];
    const float* bout = (const float*)d_in[18];
    float* outp = (float*)d_out;

    char* pb = (char*)d_ws;
    float* feat = (float*)pb;  pb += (size_t)2 * NN * 128 * 4;   // [2][NN][128]
    float* hbuf = (float*)pb;  pb += (size_t)NN * 128 * 4;
    float* el   = (float*)pb;  pb += (size_t)2 * NN * HH * 4;
    float* er   = (float*)pb;  pb += (size_t)2 * NN * HH * 4;
    int* deg    = (int*)pb;    pb += (size_t)2 * NN * 4;
    int* cursor = (int*)pb;    pb += (size_t)2 * NN * 4;
    int* offs   = (int*)pb;    pb += (size_t)2 * (NN + 1) * 4;
    int* csr    = (int*)pb;    pb += (size_t)2 * EE * 4;
    // ~50 MB total

    // ---- CSR build (once per call) ----
    hipMemsetAsync(deg, 0, (size_t)2 * NN * sizeof(int), stream);
    hist_k<<<dim3((EE + 255) / 256, 2), 256, 0, stream>>>(dst0, dst1, deg);
    scan_k<<<2, 256, 0, stream>>>(deg, offs, cursor);
    scatter_k<<<dim3((EE + 255) / 256, 2), 256, 0, stream>>>(src0, dst0, src1, dst1, cursor, csr);

    // ---- 3 GAT layers ----
    const float* hin = x;
    for (int l = 0; l < 3; ++l) {
        gemm128<<<dim3((NN + 31) / 32, 2), 256, 0, stream>>>(hin, W[l], feat);
        eler_k<<<dim3((NN * HH + 255) / 256, 2), 256, 0, stream>>>(feat, al[l], ar[l], el, er);
        pull_agg_k<<<NN / 4, 256, 0, stream>>>(csr, offs, el, er, feat,
                                               bb[l], bb[l] + 128, hbuf, (l < 2) ? 1 : 0);
        hin = hbuf;
    }
    out_gemm_k<<<NN / 16, 256, 0, stream>>>(hbuf, Wout, bout, outp);
}

// Round 3
// 531.898 us; speedup vs baseline: 3.1943x; 2.2020x over previous
//
#include <hip/hip_runtime.h>

#define NN 30000
#define EE 300000
#define HH 4
#define SLOPE 0.2f

// ---------------- GEMM v2: out[t][n][m] = sum_k A[n][k] * W[t][k][m]  (K=M=128) ----------------
// 128x128 output tile per block, K-step 32, 256 threads = 16x16, each computing 8x8 in registers.
// As is k-major so per-k fragment reads are ds_read_b128 (16-lane broadcast, conflict-free).
__global__ __launch_bounds__(256) void gemm128v2(const float* __restrict__ A,
                                                 const float* __restrict__ Wbase,
                                                 float* __restrict__ outbase) {
    __shared__ float As[32][132];   // [k][row], stride 132: read banks (4k+8tr) conflict-free
    __shared__ float Ws[32][128];   // [k][col]
    const float* W = Wbase + blockIdx.y * 128 * 128;
    float* out = outbase + (size_t)blockIdx.y * NN * 128;
    const int row0 = blockIdx.x * 128;
    const int t = threadIdx.x;
    const int tr = t >> 4, tc = t & 15;      // 16x16; thread owns rows tr*8+, cols tc*8+
    float acc[8][8];
    #pragma unroll
    for (int i = 0; i < 8; ++i)
        #pragma unroll
        for (int j = 0; j < 8; ++j) acc[i][j] = 0.f;

    for (int ks = 0; ks < 4; ++ks) {
        if (ks) __syncthreads();             // previous-iter LDS reads done
        // A tile: 128 rows x 32 k = 1024 float4s; transpose into As[k][row]
        #pragma unroll
        for (int j = 0; j < 4; ++j) {
            const int f4 = t + j * 256;
            const int r = f4 >> 3, c4 = f4 & 7;
            const int row = row0 + r;
            float4 v = make_float4(0.f, 0.f, 0.f, 0.f);
            if (row < NN) v = reinterpret_cast<const float4*>(A)[row * 32 + ks * 8 + c4];
            As[c4 * 4 + 0][r] = v.x;
            As[c4 * 4 + 1][r] = v.y;
            As[c4 * 4 + 2][r] = v.z;
            As[c4 * 4 + 3][r] = v.w;
        }
        // W tile: 32 k x 128 cols = 1024 float4s
        #pragma unroll
        for (int j = 0; j < 4; ++j) {
            const int f4 = t + j * 256;
            const int kk = f4 >> 5, c4 = f4 & 31;
            *reinterpret_cast<float4*>(&Ws[kk][c4 * 4]) =
                reinterpret_cast<const float4*>(W)[(ks * 32 + kk) * 32 + c4];
        }
        __syncthreads();
        #pragma unroll 8
        for (int k = 0; k < 32; ++k) {
            float a[8], w[8];
            *reinterpret_cast<float4*>(&a[0]) = *reinterpret_cast<const float4*>(&As[k][tr * 8]);
            *reinterpret_cast<float4*>(&a[4]) = *reinterpret_cast<const float4*>(&As[k][tr * 8 + 4]);
            *reinterpret_cast<float4*>(&w[0]) = *reinterpret_cast<const float4*>(&Ws[k][tc * 8]);
            *reinterpret_cast<float4*>(&w[4]) = *reinterpret_cast<const float4*>(&Ws[k][tc * 8 + 4]);
            #pragma unroll
            for (int i = 0; i < 8; ++i)
                #pragma unroll
                for (int j = 0; j < 8; ++j)
                    acc[i][j] = fmaf(a[i], w[j], acc[i][j]);
        }
    }
    #pragma unroll
    for (int i = 0; i < 8; ++i) {
        const int row = row0 + tr * 8 + i;
        if (row < NN) {
            float4* o = reinterpret_cast<float4*>(out + (size_t)row * 128 + tc * 8);
            o[0] = make_float4(acc[i][0], acc[i][1], acc[i][2], acc[i][3]);
            o[1] = make_float4(acc[i][4], acc[i][5], acc[i][6], acc[i][7]);
        }
    }
}

// ---------------- el/er per (node, head); grid.y = etype ----------------
__global__ __launch_bounds__(256) void eler_k(const float* __restrict__ featbase,
                                              const float* __restrict__ albase,
                                              const float* __restrict__ arbase,
                                              float* __restrict__ elbase,
                                              float* __restrict__ erbase) {
    const int gid = blockIdx.x * 256 + threadIdx.x;   // n*HH + h
    if (gid >= NN * HH) return;
    const int t = blockIdx.y;
    const float* feat = featbase + (size_t)t * NN * 128;
    const float* al = albase + t * 128;
    const float* ar = arbase + t * 128;
    const int n = gid >> 2, h = gid & 3;
    const float4* f = reinterpret_cast<const float4*>(feat + n * 128 + h * 32);
    const float4* a = reinterpret_cast<const float4*>(al + h * 32);
    const float4* b = reinterpret_cast<const float4*>(ar + h * 32);
    float sl = 0.f, sr = 0.f;
    #pragma unroll
    for (int j = 0; j < 8; ++j) {
        const float4 fv = f[j], av = a[j], bv = b[j];
        sl += fv.x * av.x + fv.y * av.y + fv.z * av.z + fv.w * av.w;
        sr += fv.x * bv.x + fv.y * bv.y + fv.z * bv.z + fv.w * bv.w;
    }
    (elbase + t * NN * HH)[gid] = sl;
    (erbase + t * NN * HH)[gid] = sr;
}

// ---------------- CSR build ----------------
__global__ __launch_bounds__(256) void hist_k(const int* __restrict__ dst0,
                                              const int* __restrict__ dst1,
                                              int* __restrict__ deg) {
    const int e = blockIdx.x * 256 + threadIdx.x;
    if (e >= EE) return;
    const int t = blockIdx.y;
    const int* d = t ? dst1 : dst0;
    atomicAdd(&deg[t * NN + d[e]], 1);
}

__global__ __launch_bounds__(256) void scan_k(const int* __restrict__ deg,
                                              int* __restrict__ offs,
                                              int* __restrict__ cursor) {
    const int t = blockIdx.x;
    const int* d = deg + t * NN;
    int* o = offs + t * (NN + 1);
    int* cur = cursor + t * NN;
    __shared__ int buf[256];
    __shared__ int carry;
    if (threadIdx.x == 0) carry = 0;
    __syncthreads();
    for (int base = 0; base < NN; base += 256) {
        const int i = base + threadIdx.x;
        const int v = (i < NN) ? d[i] : 0;
        buf[threadIdx.x] = v;
        __syncthreads();
        #pragma unroll
        for (int ofs = 1; ofs < 256; ofs <<= 1) {
            const int add = (threadIdx.x >= (unsigned)ofs) ? buf[threadIdx.x - ofs] : 0;
            __syncthreads();
            buf[threadIdx.x] += add;
            __syncthreads();
        }
        const int inc = buf[threadIdx.x];
        const int exc = carry + inc - v;
        if (i < NN) { o[i] = exc; cur[i] = exc; }
        __syncthreads();
        if (threadIdx.x == 255) carry += inc;
        __syncthreads();
    }
    if (threadIdx.x == 0) o[NN] = carry;
}

__global__ __launch_bounds__(256) void scatter_k(const int* __restrict__ src0,
                                                 const int* __restrict__ dst0,
                                                 const int* __restrict__ src1,
                                                 const int* __restrict__ dst1,
                                                 int* __restrict__ cursor,
                                                 int* __restrict__ csr_src) {
    const int e = blockIdx.x * 256 + threadIdx.x;
    if (e >= EE) return;
    const int t = blockIdx.y;
    const int* s = t ? src1 : src0;
    const int* d = t ? dst1 : dst0;
    const int pos = atomicAdd(&cursor[t * NN + d[e]], 1);
    csr_src[t * EE + pos] = s[e];
}

// ---------------- pull-mode fused softmax+aggregate+bias(+relu): one wave per node ----------------
__global__ __launch_bounds__(256) void pull_agg_k(const int* __restrict__ csr_src,
                                                  const int* __restrict__ offs,
                                                  const float* __restrict__ el,
                                                  const float* __restrict__ er,
                                                  const float* __restrict__ feat,
                                                  const float* __restrict__ b0,
                                                  const float* __restrict__ b1,
                                                  float* __restrict__ out, int relu) {
    const int wave = (blockIdx.x * 256 + threadIdx.x) >> 6;
    const int lane = threadIdx.x & 63;
    if (wave >= NN) return;
    const int n = wave;
    const int c0 = lane * 2;        // this lane owns cols c0, c0+1
    const int h = c0 >> 5;          // head for both cols
    float a0 = 0.f, a1 = 0.f;
    #pragma unroll
    for (int t = 0; t < 2; ++t) {
        const int* so = offs + t * (NN + 1);
        const int e0 = so[n], e1 = so[n + 1];
        const float erh = er[t * NN * HH + n * HH + h];
        const int* cs = csr_src + t * EE;
        const float* ft = feat + (size_t)t * NN * 128;
        const float* elt = el + t * NN * HH;
        float sA = 0.f, x0A = 0.f, x1A = 0.f;
        float sB = 0.f, x0B = 0.f, x1B = 0.f;
        int e = e0;
        for (; e + 1 < e1; e += 2) {
            const int sa = cs[e], sb = cs[e + 1];
            float va = elt[sa * HH + h] + erh;
            float vb = elt[sb * HH + h] + erh;
            va = (va >= 0.f) ? va : va * SLOPE;
            vb = (vb >= 0.f) ? vb : vb * SLOPE;
            const float ea = __expf(va);
            const float eb = __expf(vb);
            const float2 fa = *reinterpret_cast<const float2*>(ft + (size_t)sa * 128 + c0);
            const float2 fb = *reinterpret_cast<const float2*>(ft + (size_t)sb * 128 + c0);
            sA += ea; x0A = fmaf(ea, fa.x, x0A); x1A = fmaf(ea, fa.y, x1A);
            sB += eb; x0B = fmaf(eb, fb.x, x0B); x1B = fmaf(eb, fb.y, x1B);
        }
        if (e < e1) {
            const int sa = cs[e];
            float va = elt[sa * HH + h] + erh;
            va = (va >= 0.f) ? va : va * SLOPE;
            const float ea = __expf(va);
            const float2 fa = *reinterpret_cast<const float2*>(ft + (size_t)sa * 128 + c0);
            sA += ea; x0A = fmaf(ea, fa.x, x0A); x1A = fmaf(ea, fa.y, x1A);
        }
        const float s = sA + sB;
        const float x0 = x0A + x0B, x1 = x1A + x1B;
        const float inv = (s > 0.f) ? 1.f / s : 0.f;   // isolated node -> 0, matches ref
        a0 = fmaf(x0, inv, a0);
        a1 = fmaf(x1, inv, a1);
    }
    a0 += b0[c0] + b1[c0];
    a1 += b0[c0 + 1] + b1[c0 + 1];
    if (relu) { a0 = fmaxf(a0, 0.f); a1 = fmaxf(a1, 0.f); }
    *reinterpret_cast<float2*>(out + (size_t)n * 128 + c0) = make_float2(a0, a1);
}

// ---------------- final linear ----------------
__global__ __launch_bounds__(256) void out_gemm_k(const float* __restrict__ A,
                                                  const float* __restrict__ W,
                                                  const float* __restrict__ bout,
                                                  float* __restrict__ out) {
    __shared__ float At[16][132];
    const int row0 = blockIdx.x * 16;
    const int t = threadIdx.x;
    for (int i = t; i < 16 * 32; i += 256) {
        const int r = i >> 5, c4 = i & 31;
        *reinterpret_cast<float4*>(&At[r][c4 * 4]) =
            reinterpret_cast<const float4*>(A)[(row0 + r) * 32 + c4];
    }
    __syncthreads();
    const int r = t >> 4, c = t & 15;
    float accv = 0.f;
    #pragma unroll 8
    for (int k = 0; k < 128; ++k) accv = fmaf(At[r][k], W[k * 16 + c], accv);
    out[(row0 + r) * 16 + c] = accv + bout[c];
}

extern "C" void kernel_launch(void* const* d_in, const int* in_sizes, int n_in,
                              void* d_out, int out_size, void* d_ws, size_t ws_size,
                              hipStream_t stream) {
    (void)in_sizes; (void)n_in; (void)out_size; (void)ws_size;
    const float* x = (const float*)d_in[0];
    const int* src0 = (const int*)d_in[1];
    const int* dst0 = (const int*)d_in[2];
    const int* src1 = (const int*)d_in[3];
    const int* dst1 = (const int*)d_in[4];
    const float* W[3]  = {(const float*)d_in[5], (const float*)d_in[9],  (const float*)d_in[13]};
    const float* al[3] = {(const float*)d_in[6], (const float*)d_in[10], (const float*)d_in[14]};
    const float* ar[3] = {(const float*)d_in[7], (const float*)d_in[11], (const float*)d_in[15]};
    const float* bb[3] = {(const float*)d_in[8], (const float*)d_in[12], (const float*)d_in[16]};
    const float* Wout = (const float*)d_in[17];
    const float* bout = (const float*)d_in[18];
    float* outp = (float*)d_out;

    char* pb = (char*)d_ws;
    float* feat = (float*)pb;  pb += (size_t)2 * NN * 128 * 4;   // [2][NN][128]
    float* hbuf = (float*)pb;  pb += (size_t)NN * 128 * 4;
    float* el   = (float*)pb;  pb += (size_t)2 * NN * HH * 4;
    float* er   = (float*)pb;  pb += (size_t)2 * NN * HH * 4;
    int* deg    = (int*)pb;    pb += (size_t)2 * NN * 4;
    int* cursor = (int*)pb;    pb += (size_t)2 * NN * 4;
    int* offs   = (int*)pb;    pb += (size_t)2 * (NN + 1) * 4;
    int* csr    = (int*)pb;    pb += (size_t)2 * EE * 4;

    // ---- CSR build (once per call) ----
    hipMemsetAsync(deg, 0, (size_t)2 * NN * sizeof(int), stream);
    hist_k<<<dim3((EE + 255) / 256, 2), 256, 0, stream>>>(dst0, dst1, deg);
    scan_k<<<2, 256, 0, stream>>>(deg, offs, cursor);
    scatter_k<<<dim3((EE + 255) / 256, 2), 256, 0, stream>>>(src0, dst0, src1, dst1, cursor, csr);

    // ---- 3 GAT layers ----
    const float* hin = x;
    for (int l = 0; l < 3; ++l) {
        gemm128v2<<<dim3((NN + 127) / 128, 2), 256, 0, stream>>>(hin, W[l], feat);
        eler_k<<<dim3((NN * HH + 255) / 256, 2), 256, 0, stream>>>(feat, al[l], ar[l], el, er);
        pull_agg_k<<<NN / 4, 256, 0, stream>>>(csr, offs, el, er, feat,
                                               bb[l], bb[l] + 128, hbuf, (l < 2) ? 1 : 0);
        hin = hbuf;
    }
    out_gemm_k<<<NN / 16, 256, 0, stream>>>(hbuf, Wout, bout, outp);
}

// Round 4
// 407.005 us; speedup vs baseline: 4.1745x; 1.3069x over previous
//
#include <hip/hip_runtime.h>

#define NN 30000
#define EE 300000
#define HH 4
#define SLOPE 0.2f
#define SCAN_NB 15        // ceil(30000 / 2048)

// ---------------- GEMM v2: out[t][n][m] = sum_k A[n][k] * W[t][k][m]  (K=M=128) ----------------
// 128x128 output tile per block, K-step 32, 256 threads = 16x16, each computing 8x8 in registers.
__global__ __launch_bounds__(256) void gemm128v2(const float* __restrict__ A,
                                                 const float* __restrict__ Wbase,
                                                 float* __restrict__ outbase) {
    __shared__ float As[32][132];   // [k][row]
    __shared__ float Ws[32][128];   // [k][col]
    const float* W = Wbase + blockIdx.y * 128 * 128;
    float* out = outbase + (size_t)blockIdx.y * NN * 128;
    const int row0 = blockIdx.x * 128;
    const int t = threadIdx.x;
    const int tr = t >> 4, tc = t & 15;
    float acc[8][8];
    #pragma unroll
    for (int i = 0; i < 8; ++i)
        #pragma unroll
        for (int j = 0; j < 8; ++j) acc[i][j] = 0.f;

    for (int ks = 0; ks < 4; ++ks) {
        if (ks) __syncthreads();
        #pragma unroll
        for (int j = 0; j < 4; ++j) {
            const int f4 = t + j * 256;
            const int r = f4 >> 3, c4 = f4 & 7;
            const int row = row0 + r;
            float4 v = make_float4(0.f, 0.f, 0.f, 0.f);
            if (row < NN) v = reinterpret_cast<const float4*>(A)[row * 32 + ks * 8 + c4];
            As[c4 * 4 + 0][r] = v.x;
            As[c4 * 4 + 1][r] = v.y;
            As[c4 * 4 + 2][r] = v.z;
            As[c4 * 4 + 3][r] = v.w;
        }
        #pragma unroll
        for (int j = 0; j < 4; ++j) {
            const int f4 = t + j * 256;
            const int kk = f4 >> 5, c4 = f4 & 31;
            *reinterpret_cast<float4*>(&Ws[kk][c4 * 4]) =
                reinterpret_cast<const float4*>(W)[(ks * 32 + kk) * 32 + c4];
        }
        __syncthreads();
        #pragma unroll 8
        for (int k = 0; k < 32; ++k) {
            float a[8], w[8];
            *reinterpret_cast<float4*>(&a[0]) = *reinterpret_cast<const float4*>(&As[k][tr * 8]);
            *reinterpret_cast<float4*>(&a[4]) = *reinterpret_cast<const float4*>(&As[k][tr * 8 + 4]);
            *reinterpret_cast<float4*>(&w[0]) = *reinterpret_cast<const float4*>(&Ws[k][tc * 8]);
            *reinterpret_cast<float4*>(&w[4]) = *reinterpret_cast<const float4*>(&Ws[k][tc * 8 + 4]);
            #pragma unroll
            for (int i = 0; i < 8; ++i)
                #pragma unroll
                for (int j = 0; j < 8; ++j)
                    acc[i][j] = fmaf(a[i], w[j], acc[i][j]);
        }
    }
    #pragma unroll
    for (int i = 0; i < 8; ++i) {
        const int row = row0 + tr * 8 + i;
        if (row < NN) {
            float4* o = reinterpret_cast<float4*>(out + (size_t)row * 128 + tc * 8);
            o[0] = make_float4(acc[i][0], acc[i][1], acc[i][2], acc[i][3]);
            o[1] = make_float4(acc[i][4], acc[i][5], acc[i][6], acc[i][7]);
        }
    }
}

// ---------------- el/er per (node, head); grid.y = etype ----------------
__global__ __launch_bounds__(256) void eler_k(const float* __restrict__ featbase,
                                              const float* __restrict__ albase,
                                              const float* __restrict__ arbase,
                                              float* __restrict__ elbase,
                                              float* __restrict__ erbase) {
    const int gid = blockIdx.x * 256 + threadIdx.x;   // n*HH + h
    if (gid >= NN * HH) return;
    const int t = blockIdx.y;
    const float* feat = featbase + (size_t)t * NN * 128;
    const float* al = albase + t * 128;
    const float* ar = arbase + t * 128;
    const int n = gid >> 2, h = gid & 3;
    const float4* f = reinterpret_cast<const float4*>(feat + n * 128 + h * 32);
    const float4* a = reinterpret_cast<const float4*>(al + h * 32);
    const float4* b = reinterpret_cast<const float4*>(ar + h * 32);
    float sl = 0.f, sr = 0.f;
    #pragma unroll
    for (int j = 0; j < 8; ++j) {
        const float4 fv = f[j], av = a[j], bv = b[j];
        sl += fv.x * av.x + fv.y * av.y + fv.z * av.z + fv.w * av.w;
        sr += fv.x * bv.x + fv.y * bv.y + fv.z * bv.z + fv.w * bv.w;
    }
    (elbase + t * NN * HH)[gid] = sl;
    (erbase + t * NN * HH)[gid] = sr;
}

// ---------------- CSR build: histogram (grid.y = etype) ----------------
__global__ __launch_bounds__(256) void hist_k(const int* __restrict__ dst0,
                                              const int* __restrict__ dst1,
                                              int* __restrict__ deg) {
    const int e = blockIdx.x * 256 + threadIdx.x;
    if (e >= EE) return;
    const int t = blockIdx.y;
    const int* d = t ? dst1 : dst0;
    atomicAdd(&deg[t * NN + d[e]], 1);
}

// ---------------- multi-block exclusive scan, phase 1: per-chunk scan + block sums ----------------
// grid = (SCAN_NB, 2); each block scans 2048 elements (8 per thread).
__global__ __launch_bounds__(256) void scan1_k(const int* __restrict__ deg,
                                               int* __restrict__ offs,
                                               int* __restrict__ blocksum) {
    const int t = blockIdx.y, b = blockIdx.x;
    const int* d = deg + t * NN;
    int* o = offs + t * (NN + 1);
    const int base = b * 2048 + threadIdx.x * 8;
    int v[8];
    int s = 0;
    #pragma unroll
    for (int j = 0; j < 8; ++j) {
        const int i = base + j;
        v[j] = (i < NN) ? d[i] : 0;
        s += v[j];
    }
    __shared__ int buf[256];
    buf[threadIdx.x] = s;
    __syncthreads();
    #pragma unroll
    for (int ofs = 1; ofs < 256; ofs <<= 1) {
        const int add = (threadIdx.x >= (unsigned)ofs) ? buf[threadIdx.x - ofs] : 0;
        __syncthreads();
        buf[threadIdx.x] += add;
        __syncthreads();
    }
    int run = buf[threadIdx.x] - s;   // exclusive offset of this thread within block
    #pragma unroll
    for (int j = 0; j < 8; ++j) {
        const int i = base + j;
        if (i < NN) o[i] = run;
        run += v[j];
    }
    if (threadIdx.x == 255) blocksum[t * SCAN_NB + b] = buf[255];
}

// ---------------- scan phase 2: serial scan of 2*SCAN_NB block sums (tiny) ----------------
__global__ __launch_bounds__(64) void scan2_k(int* __restrict__ blocksum,
                                              int* __restrict__ offs) {
    if (threadIdx.x != 0) return;
    #pragma unroll
    for (int t = 0; t < 2; ++t) {
        int run = 0;
        for (int b = 0; b < SCAN_NB; ++b) {
            const int v = blocksum[t * SCAN_NB + b];
            blocksum[t * SCAN_NB + b] = run;   // becomes block offset
            run += v;
        }
        offs[t * (NN + 1) + NN] = run;         // = EE
    }
}

// ---------------- scan phase 3: add block offsets, materialize cursor ----------------
__global__ __launch_bounds__(256) void scan3_k(int* __restrict__ offs,
                                               const int* __restrict__ blocksum,
                                               int* __restrict__ cursor) {
    const int t = blockIdx.y, b = blockIdx.x;
    const int boff = blocksum[t * SCAN_NB + b];
    int* o = offs + t * (NN + 1);
    int* cur = cursor + t * NN;
    const int base = b * 2048 + threadIdx.x * 8;
    #pragma unroll
    for (int j = 0; j < 8; ++j) {
        const int i = base + j;
        if (i < NN) {
            const int val = o[i] + boff;
            o[i] = val;
            cur[i] = val;
        }
    }
}

// ---------------- CSR build: scatter src into dst-sorted order (grid.y = etype) ----------------
__global__ __launch_bounds__(256) void scatter_k(const int* __restrict__ src0,
                                                 const int* __restrict__ dst0,
                                                 const int* __restrict__ src1,
                                                 const int* __restrict__ dst1,
                                                 int* __restrict__ cursor,
                                                 int* __restrict__ csr_src) {
    const int e = blockIdx.x * 256 + threadIdx.x;
    if (e >= EE) return;
    const int t = blockIdx.y;
    const int* s = t ? src1 : src0;
    const int* d = t ? dst1 : dst0;
    const int pos = atomicAdd(&cursor[t * NN + d[e]], 1);
    csr_src[t * EE + pos] = s[e];
}

// ---------------- pull-mode fused softmax+aggregate+bias(+relu): one wave per node ----------------
__global__ __launch_bounds__(256) void pull_agg_k(const int* __restrict__ csr_src,
                                                  const int* __restrict__ offs,
                                                  const float* __restrict__ el,
                                                  const float* __restrict__ er,
                                                  const float* __restrict__ feat,
                                                  const float* __restrict__ b0,
                                                  const float* __restrict__ b1,
                                                  float* __restrict__ out, int relu) {
    const int wave = (blockIdx.x * 256 + threadIdx.x) >> 6;
    const int lane = threadIdx.x & 63;
    if (wave >= NN) return;
    const int n = wave;
    const int c0 = lane * 2;
    const int h = c0 >> 5;
    float a0 = 0.f, a1 = 0.f;
    #pragma unroll
    for (int t = 0; t < 2; ++t) {
        const int* so = offs + t * (NN + 1);
        const int e0 = so[n], e1 = so[n + 1];
        const float erh = er[t * NN * HH + n * HH + h];
        const int* cs = csr_src + t * EE;
        const float* ft = feat + (size_t)t * NN * 128;
        const float* elt = el + t * NN * HH;
        float sA = 0.f, x0A = 0.f, x1A = 0.f;
        float sB = 0.f, x0B = 0.f, x1B = 0.f;
        int e = e0;
        for (; e + 1 < e1; e += 2) {
            const int sa = cs[e], sb = cs[e + 1];
            float va = elt[sa * HH + h] + erh;
            float vb = elt[sb * HH + h] + erh;
            va = (va >= 0.f) ? va : va * SLOPE;
            vb = (vb >= 0.f) ? vb : vb * SLOPE;
            const float ea = __expf(va);
            const float eb = __expf(vb);
            const float2 fa = *reinterpret_cast<const float2*>(ft + (size_t)sa * 128 + c0);
            const float2 fb = *reinterpret_cast<const float2*>(ft + (size_t)sb * 128 + c0);
            sA += ea; x0A = fmaf(ea, fa.x, x0A); x1A = fmaf(ea, fa.y, x1A);
            sB += eb; x0B = fmaf(eb, fb.x, x0B); x1B = fmaf(eb, fb.y, x1B);
        }
        if (e < e1) {
            const int sa = cs[e];
            float va = elt[sa * HH + h] + erh;
            va = (va >= 0.f) ? va : va * SLOPE;
            const float ea = __expf(va);
            const float2 fa = *reinterpret_cast<const float2*>(ft + (size_t)sa * 128 + c0);
            sA += ea; x0A = fmaf(ea, fa.x, x0A); x1A = fmaf(ea, fa.y, x1A);
        }
        const float s = sA + sB;
        const float x0 = x0A + x0B, x1 = x1A + x1B;
        const float inv = (s > 0.f) ? 1.f / s : 0.f;
        a0 = fmaf(x0, inv, a0);
        a1 = fmaf(x1, inv, a1);
    }
    a0 += b0[c0] + b1[c0];
    a1 += b0[c0 + 1] + b1[c0 + 1];
    if (relu) { a0 = fmaxf(a0, 0.f); a1 = fmaxf(a1, 0.f); }
    *reinterpret_cast<float2*>(out + (size_t)n * 128 + c0) = make_float2(a0, a1);
}

// ---------------- final linear ----------------
__global__ __launch_bounds__(256) void out_gemm_k(const float* __restrict__ A,
                                                  const float* __restrict__ W,
                                                  const float* __restrict__ bout,
                                                  float* __restrict__ out) {
    __shared__ float At[16][132];
    const int row0 = blockIdx.x * 16;
    const int t = threadIdx.x;
    for (int i = t; i < 16 * 32; i += 256) {
        const int r = i >> 5, c4 = i & 31;
        *reinterpret_cast<float4*>(&At[r][c4 * 4]) =
            reinterpret_cast<const float4*>(A)[(row0 + r) * 32 + c4];
    }
    __syncthreads();
    const int r = t >> 4, c = t & 15;
    float accv = 0.f;
    #pragma unroll 8
    for (int k = 0; k < 128; ++k) accv = fmaf(At[r][k], W[k * 16 + c], accv);
    out[(row0 + r) * 16 + c] = accv + bout[c];
}

extern "C" void kernel_launch(void* const* d_in, const int* in_sizes, int n_in,
                              void* d_out, int out_size, void* d_ws, size_t ws_size,
                              hipStream_t stream) {
    (void)in_sizes; (void)n_in; (void)out_size; (void)ws_size;
    const float* x = (const float*)d_in[0];
    const int* src0 = (const int*)d_in[1];
    const int* dst0 = (const int*)d_in[2];
    const int* src1 = (const int*)d_in[3];
    const int* dst1 = (const int*)d_in[4];
    const float* W[3]  = {(const float*)d_in[5], (const float*)d_in[9],  (const float*)d_in[13]};
    const float* al[3] = {(const float*)d_in[6], (const float*)d_in[10], (const float*)d_in[14]};
    const float* ar[3] = {(const float*)d_in[7], (const float*)d_in[11], (const float*)d_in[15]};
    const float* bb[3] = {(const float*)d_in[8], (const float*)d_in[12], (const float*)d_in[16]};
    const float* Wout = (const float*)d_in[17];
    const float* bout = (const float*)d_in[18];
    float* outp = (float*)d_out;

    char* pb = (char*)d_ws;
    float* feat = (float*)pb;  pb += (size_t)2 * NN * 128 * 4;
    float* hbuf = (float*)pb;  pb += (size_t)NN * 128 * 4;
    float* el   = (float*)pb;  pb += (size_t)2 * NN * HH * 4;
    float* er   = (float*)pb;  pb += (size_t)2 * NN * HH * 4;
    int* deg    = (int*)pb;    pb += (size_t)2 * NN * 4;
    int* cursor = (int*)pb;    pb += (size_t)2 * NN * 4;
    int* offs   = (int*)pb;    pb += (size_t)2 * (NN + 1) * 4;
    int* bsum   = (int*)pb;    pb += (size_t)2 * SCAN_NB * 4;
    int* csr    = (int*)pb;    pb += (size_t)2 * EE * 4;

    // ---- CSR build (once per call) ----
    hipMemsetAsync(deg, 0, (size_t)2 * NN * sizeof(int), stream);
    hist_k<<<dim3((EE + 255) / 256, 2), 256, 0, stream>>>(dst0, dst1, deg);
    scan1_k<<<dim3(SCAN_NB, 2), 256, 0, stream>>>(deg, offs, bsum);
    scan2_k<<<1, 64, 0, stream>>>(bsum, offs);
    scan3_k<<<dim3(SCAN_NB, 2), 256, 0, stream>>>(offs, bsum, cursor);
    scatter_k<<<dim3((EE + 255) / 256, 2), 256, 0, stream>>>(src0, dst0, src1, dst1, cursor, csr);

    // ---- 3 GAT layers ----
    const float* hin = x;
    for (int l = 0; l < 3; ++l) {
        gemm128v2<<<dim3((NN + 127) / 128, 2), 256, 0, stream>>>(hin, W[l], feat);
        eler_k<<<dim3((NN * HH + 255) / 256, 2), 256, 0, stream>>>(feat, al[l], ar[l], el, er);
        pull_agg_k<<<NN / 4, 256, 0, stream>>>(csr, offs, el, er, feat,
                                               bb[l], bb[l] + 128, hbuf, (l < 2) ? 1 : 0);
        hin = hbuf;
    }
    out_gemm_k<<<NN / 16, 256, 0, stream>>>(hbuf, Wout, bout, outp);
}

// Round 5
// 299.534 us; speedup vs baseline: 5.6723x; 1.3588x over previous
//
#include <hip/hip_runtime.h>

#define NN 30000
#define EE 300000
#define HH 4
#define SLOPE 0.2f
#define SCAN_NB 15        // ceil(30000 / 2048)

typedef _Float16 f16;
struct f16x2 { f16 x, y; };

// ---------------- GEMM v3: feat16[t][n][m] = A @ W[t], fused el/er epilogue ----------------
// 128x128 output tile, K-step 32, 256 threads = 16x16, 8x8 register tile each.
__global__ __launch_bounds__(256) void gemm128v3(const float* __restrict__ A,
                                                 const float* __restrict__ Wbase,
                                                 const float* __restrict__ albase,
                                                 const float* __restrict__ arbase,
                                                 f16* __restrict__ featbase,
                                                 float* __restrict__ elbase,
                                                 float* __restrict__ erbase) {
    __shared__ float As[32][132];   // [k][row]
    __shared__ float Ws[32][128];   // [k][col]
    const int et = blockIdx.y;
    const float* W = Wbase + et * 128 * 128;
    f16* feat = featbase + (size_t)et * NN * 128;
    const int row0 = blockIdx.x * 128;
    const int t = threadIdx.x;
    const int tr = t >> 4, tc = t & 15;
    float acc[8][8];
    #pragma unroll
    for (int i = 0; i < 8; ++i)
        #pragma unroll
        for (int j = 0; j < 8; ++j) acc[i][j] = 0.f;

    for (int ks = 0; ks < 4; ++ks) {
        if (ks) __syncthreads();
        #pragma unroll
        for (int j = 0; j < 4; ++j) {
            const int f4 = t + j * 256;
            const int r = f4 >> 3, c4 = f4 & 7;
            const int row = row0 + r;
            float4 v = make_float4(0.f, 0.f, 0.f, 0.f);
            if (row < NN) v = reinterpret_cast<const float4*>(A)[row * 32 + ks * 8 + c4];
            As[c4 * 4 + 0][r] = v.x;
            As[c4 * 4 + 1][r] = v.y;
            As[c4 * 4 + 2][r] = v.z;
            As[c4 * 4 + 3][r] = v.w;
        }
        #pragma unroll
        for (int j = 0; j < 4; ++j) {
            const int f4 = t + j * 256;
            const int kk = f4 >> 5, c4 = f4 & 31;
            *reinterpret_cast<float4*>(&Ws[kk][c4 * 4]) =
                reinterpret_cast<const float4*>(W)[(ks * 32 + kk) * 32 + c4];
        }
        __syncthreads();
        #pragma unroll 8
        for (int k = 0; k < 32; ++k) {
            float a[8], w[8];
            *reinterpret_cast<float4*>(&a[0]) = *reinterpret_cast<const float4*>(&As[k][tr * 8]);
            *reinterpret_cast<float4*>(&a[4]) = *reinterpret_cast<const float4*>(&As[k][tr * 8 + 4]);
            *reinterpret_cast<float4*>(&w[0]) = *reinterpret_cast<const float4*>(&Ws[k][tc * 8]);
            *reinterpret_cast<float4*>(&w[4]) = *reinterpret_cast<const float4*>(&Ws[k][tc * 8 + 4]);
            #pragma unroll
            for (int i = 0; i < 8; ++i)
                #pragma unroll
                for (int j = 0; j < 8; ++j)
                    acc[i][j] = fmaf(a[i], w[j], acc[i][j]);
        }
    }

    // epilogue: fp16 feat store + fused el/er (dot with al/ar, 4-lane quad reduce)
    float alv[8], arv[8];
    #pragma unroll
    for (int j = 0; j < 8; ++j) {
        alv[j] = albase[et * 128 + tc * 8 + j];
        arv[j] = arbase[et * 128 + tc * 8 + j];
    }
    const int hh = tc >> 2;         // head this quad contributes to
    #pragma unroll
    for (int i = 0; i < 8; ++i) {
        const int row = row0 + tr * 8 + i;
        float pl = 0.f, pr = 0.f;
        #pragma unroll
        for (int j = 0; j < 8; ++j) {
            pl = fmaf(acc[i][j], alv[j], pl);
            pr = fmaf(acc[i][j], arv[j], pr);
        }
        pl += __shfl_xor(pl, 1); pl += __shfl_xor(pl, 2);
        pr += __shfl_xor(pr, 1); pr += __shfl_xor(pr, 2);
        if (row < NN) {
            union { f16 h[8]; float4 f4; } pk;
            #pragma unroll
            for (int j = 0; j < 8; ++j) pk.h[j] = (f16)acc[i][j];
            *reinterpret_cast<float4*>(feat + (size_t)row * 128 + tc * 8) = pk.f4;
            if ((tc & 3) == 0) {
                elbase[et * NN * HH + row * HH + hh] = pl;
                erbase[et * NN * HH + row * HH + hh] = pr;
            }
        }
    }
}

// ---------------- CSR build: histogram (grid.y = etype) ----------------
__global__ __launch_bounds__(256) void hist_k(const int* __restrict__ dst0,
                                              const int* __restrict__ dst1,
                                              int* __restrict__ deg) {
    const int e = blockIdx.x * 256 + threadIdx.x;
    if (e >= EE) return;
    const int t = blockIdx.y;
    const int* d = t ? dst1 : dst0;
    atomicAdd(&deg[t * NN + d[e]], 1);
}

// ---------------- multi-block exclusive scan ----------------
__global__ __launch_bounds__(256) void scan1_k(const int* __restrict__ deg,
                                               int* __restrict__ offs,
                                               int* __restrict__ blocksum) {
    const int t = blockIdx.y, b = blockIdx.x;
    const int* d = deg + t * NN;
    int* o = offs + t * (NN + 1);
    const int base = b * 2048 + threadIdx.x * 8;
    int v[8];
    int s = 0;
    #pragma unroll
    for (int j = 0; j < 8; ++j) {
        const int i = base + j;
        v[j] = (i < NN) ? d[i] : 0;
        s += v[j];
    }
    __shared__ int buf[256];
    buf[threadIdx.x] = s;
    __syncthreads();
    #pragma unroll
    for (int ofs = 1; ofs < 256; ofs <<= 1) {
        const int add = (threadIdx.x >= (unsigned)ofs) ? buf[threadIdx.x - ofs] : 0;
        __syncthreads();
        buf[threadIdx.x] += add;
        __syncthreads();
    }
    int run = buf[threadIdx.x] - s;
    #pragma unroll
    for (int j = 0; j < 8; ++j) {
        const int i = base + j;
        if (i < NN) o[i] = run;
        run += v[j];
    }
    if (threadIdx.x == 255) blocksum[t * SCAN_NB + b] = buf[255];
}

__global__ __launch_bounds__(64) void scan2_k(int* __restrict__ blocksum,
                                              int* __restrict__ offs) {
    if (threadIdx.x != 0) return;
    #pragma unroll
    for (int t = 0; t < 2; ++t) {
        int run = 0;
        for (int b = 0; b < SCAN_NB; ++b) {
            const int v = blocksum[t * SCAN_NB + b];
            blocksum[t * SCAN_NB + b] = run;
            run += v;
        }
        offs[t * (NN + 1) + NN] = run;
    }
}

__global__ __launch_bounds__(256) void scan3_k(int* __restrict__ offs,
                                               const int* __restrict__ blocksum,
                                               int* __restrict__ cursor) {
    const int t = blockIdx.y, b = blockIdx.x;
    const int boff = blocksum[t * SCAN_NB + b];
    int* o = offs + t * (NN + 1);
    int* cur = cursor + t * NN;
    const int base = b * 2048 + threadIdx.x * 8;
    #pragma unroll
    for (int j = 0; j < 8; ++j) {
        const int i = base + j;
        if (i < NN) {
            const int val = o[i] + boff;
            o[i] = val;
            cur[i] = val;
        }
    }
}

__global__ __launch_bounds__(256) void scatter_k(const int* __restrict__ src0,
                                                 const int* __restrict__ dst0,
                                                 const int* __restrict__ src1,
                                                 const int* __restrict__ dst1,
                                                 int* __restrict__ cursor,
                                                 int* __restrict__ csr_src) {
    const int e = blockIdx.x * 256 + threadIdx.x;
    if (e >= EE) return;
    const int t = blockIdx.y;
    const int* s = t ? src1 : src0;
    const int* d = t ? dst1 : dst0;
    const int pos = atomicAdd(&cursor[t * NN + d[e]], 1);
    csr_src[t * EE + pos] = s[e];
}

// ---------------- pull-mode fused softmax+aggregate+bias(+relu): one wave per node ----------------
__global__ __launch_bounds__(256) void pull_agg_k(const int* __restrict__ csr_src,
                                                  const int* __restrict__ offs,
                                                  const float* __restrict__ el,
                                                  const float* __restrict__ er,
                                                  const f16* __restrict__ feat,
                                                  const float* __restrict__ b0,
                                                  const float* __restrict__ b1,
                                                  float* __restrict__ out, int relu) {
    const int wave = (blockIdx.x * 256 + threadIdx.x) >> 6;
    const int lane = threadIdx.x & 63;
    if (wave >= NN) return;
    const int n = wave;
    const int c0 = lane * 2;
    const int h = c0 >> 5;
    float a0 = 0.f, a1 = 0.f;
    #pragma unroll
    for (int t = 0; t < 2; ++t) {
        const int* so = offs + t * (NN + 1);
        const int e0 = so[n], e1 = so[n + 1];
        const float erh = er[t * NN * HH + n * HH + h];
        const int* cs = csr_src + t * EE;
        const f16* ft = feat + (size_t)t * NN * 128;
        const float* elt = el + t * NN * HH;
        float sA = 0.f, x0A = 0.f, x1A = 0.f;
        float sB = 0.f, x0B = 0.f, x1B = 0.f;
        float sC = 0.f, x0C = 0.f, x1C = 0.f;
        float sD = 0.f, x0D = 0.f, x1D = 0.f;
        int e = e0;
        for (; e + 3 < e1; e += 4) {
            const int sa = cs[e], sb = cs[e + 1], sc = cs[e + 2], sd = cs[e + 3];
            float va = elt[sa * HH + h] + erh;
            float vb = elt[sb * HH + h] + erh;
            float vc = elt[sc * HH + h] + erh;
            float vd = elt[sd * HH + h] + erh;
            const f16x2 fa = *reinterpret_cast<const f16x2*>(ft + (size_t)sa * 128 + c0);
            const f16x2 fb = *reinterpret_cast<const f16x2*>(ft + (size_t)sb * 128 + c0);
            const f16x2 fc = *reinterpret_cast<const f16x2*>(ft + (size_t)sc * 128 + c0);
            const f16x2 fd = *reinterpret_cast<const f16x2*>(ft + (size_t)sd * 128 + c0);
            va = (va >= 0.f) ? va : va * SLOPE;
            vb = (vb >= 0.f) ? vb : vb * SLOPE;
            vc = (vc >= 0.f) ? vc : vc * SLOPE;
            vd = (vd >= 0.f) ? vd : vd * SLOPE;
            const float ea = __expf(va), eb = __expf(vb);
            const float ec = __expf(vc), ed = __expf(vd);
            sA += ea; x0A = fmaf(ea, (float)fa.x, x0A); x1A = fmaf(ea, (float)fa.y, x1A);
            sB += eb; x0B = fmaf(eb, (float)fb.x, x0B); x1B = fmaf(eb, (float)fb.y, x1B);
            sC += ec; x0C = fmaf(ec, (float)fc.x, x0C); x1C = fmaf(ec, (float)fc.y, x1C);
            sD += ed; x0D = fmaf(ed, (float)fd.x, x0D); x1D = fmaf(ed, (float)fd.y, x1D);
        }
        for (; e < e1; ++e) {
            const int sa = cs[e];
            float va = elt[sa * HH + h] + erh;
            va = (va >= 0.f) ? va : va * SLOPE;
            const float ea = __expf(va);
            const f16x2 fa = *reinterpret_cast<const f16x2*>(ft + (size_t)sa * 128 + c0);
            sA += ea; x0A = fmaf(ea, (float)fa.x, x0A); x1A = fmaf(ea, (float)fa.y, x1A);
        }
        const float s = (sA + sB) + (sC + sD);
        const float x0 = (x0A + x0B) + (x0C + x0D);
        const float x1 = (x1A + x1B) + (x1C + x1D);
        const float inv = (s > 0.f) ? 1.f / s : 0.f;
        a0 = fmaf(x0, inv, a0);
        a1 = fmaf(x1, inv, a1);
    }
    a0 += b0[c0] + b1[c0];
    a1 += b0[c0 + 1] + b1[c0 + 1];
    if (relu) { a0 = fmaxf(a0, 0.f); a1 = fmaxf(a1, 0.f); }
    *reinterpret_cast<float2*>(out + (size_t)n * 128 + c0) = make_float2(a0, a1);
}

// ---------------- final linear ----------------
__global__ __launch_bounds__(256) void out_gemm_k(const float* __restrict__ A,
                                                  const float* __restrict__ W,
                                                  const float* __restrict__ bout,
                                                  float* __restrict__ out) {
    __shared__ float At[16][132];
    const int row0 = blockIdx.x * 16;
    const int t = threadIdx.x;
    for (int i = t; i < 16 * 32; i += 256) {
        const int r = i >> 5, c4 = i & 31;
        *reinterpret_cast<float4*>(&At[r][c4 * 4]) =
            reinterpret_cast<const float4*>(A)[(row0 + r) * 32 + c4];
    }
    __syncthreads();
    const int r = t >> 4, c = t & 15;
    float accv = 0.f;
    #pragma unroll 8
    for (int k = 0; k < 128; ++k) accv = fmaf(At[r][k], W[k * 16 + c], accv);
    out[(row0 + r) * 16 + c] = accv + bout[c];
}

extern "C" void kernel_launch(void* const* d_in, const int* in_sizes, int n_in,
                              void* d_out, int out_size, void* d_ws, size_t ws_size,
                              hipStream_t stream) {
    (void)in_sizes; (void)n_in; (void)out_size; (void)ws_size;
    const float* x = (const float*)d_in[0];
    const int* src0 = (const int*)d_in[1];
    const int* dst0 = (const int*)d_in[2];
    const int* src1 = (const int*)d_in[3];
    const int* dst1 = (const int*)d_in[4];
    const float* W[3]  = {(const float*)d_in[5], (const float*)d_in[9],  (const float*)d_in[13]};
    const float* al[3] = {(const float*)d_in[6], (const float*)d_in[10], (const float*)d_in[14]};
    const float* ar[3] = {(const float*)d_in[7], (const float*)d_in[11], (const float*)d_in[15]};
    const float* bb[3] = {(const float*)d_in[8], (const float*)d_in[12], (const float*)d_in[16]};
    const float* Wout = (const float*)d_in[17];
    const float* bout = (const float*)d_in[18];
    float* outp = (float*)d_out;

    char* pb = (char*)d_ws;
    f16* feat   = (f16*)pb;    pb += (size_t)2 * NN * 128 * 2;   // [2][NN][128] fp16
    float* hbuf = (float*)pb;  pb += (size_t)NN * 128 * 4;
    float* el   = (float*)pb;  pb += (size_t)2 * NN * HH * 4;
    float* er   = (float*)pb;  pb += (size_t)2 * NN * HH * 4;
    int* deg    = (int*)pb;    pb += (size_t)2 * NN * 4;
    int* cursor = (int*)pb;    pb += (size_t)2 * NN * 4;
    int* offs   = (int*)pb;    pb += (size_t)2 * (NN + 1) * 4;
    int* bsum   = (int*)pb;    pb += (size_t)2 * SCAN_NB * 4;
    int* csr    = (int*)pb;    pb += (size_t)2 * EE * 4;

    // ---- CSR build (once per call) ----
    hipMemsetAsync(deg, 0, (size_t)2 * NN * sizeof(int), stream);
    hist_k<<<dim3((EE + 255) / 256, 2), 256, 0, stream>>>(dst0, dst1, deg);
    scan1_k<<<dim3(SCAN_NB, 2), 256, 0, stream>>>(deg, offs, bsum);
    scan2_k<<<1, 64, 0, stream>>>(bsum, offs);
    scan3_k<<<dim3(SCAN_NB, 2), 256, 0, stream>>>(offs, bsum, cursor);
    scatter_k<<<dim3((EE + 255) / 256, 2), 256, 0, stream>>>(src0, dst0, src1, dst1, cursor, csr);

    // ---- 3 GAT layers ----
    const float* hin = x;
    for (int l = 0; l < 3; ++l) {
        gemm128v3<<<dim3((NN + 127) / 128, 2), 256, 0, stream>>>(hin, W[l], al[l], ar[l],
                                                                 feat, el, er);
        pull_agg_k<<<NN / 4, 256, 0, stream>>>(csr, offs, el, er, feat,
                                               bb[l], bb[l] + 128, hbuf, (l < 2) ? 1 : 0);
        hin = hbuf;
    }
    out_gemm_k<<<NN / 16, 256, 0, stream>>>(hbuf, Wout, bout, outp);
}

// Round 7
// 271.453 us; speedup vs baseline: 6.2591x; 1.1034x over previous
//
#include <hip/hip_runtime.h>

#define NN 30000
#define EE 300000
#define HH 4
#define SLOPE 0.2f
#define SCAN_NB 15        // ceil(30000 / 2048)

typedef _Float16 f16;
struct f16x2 { f16 x, y; };
typedef f16 f16x8 __attribute__((ext_vector_type(8)));
typedef float f32x4 __attribute__((ext_vector_type(4)));

// ---------------- zero deg (the rocclr fill kernel costs 43us; this is ~2us) ----------------
__global__ __launch_bounds__(256) void zero_k(int4* __restrict__ p, int n4) {
    const int i = blockIdx.x * 256 + threadIdx.x;
    if (i < n4) p[i] = make_int4(0, 0, 0, 0);
}

// ---------------- W pre-convert: Wh[t][col][k] = (f16) W[t][k][col] ----------------
__global__ __launch_bounds__(256) void wconv_k(const float* __restrict__ W,
                                               f16* __restrict__ Wh) {
    const int t = blockIdx.y;
    const int i0 = blockIdx.x * 2048;
    #pragma unroll
    for (int j = 0; j < 8; ++j) {
        const int i = i0 + threadIdx.x + j * 256;     // i = k*128 + col (coalesced read)
        const int k = i >> 7, col = i & 127;
        Wh[t * 16384 + col * 128 + k] = (f16)W[t * 16384 + i];
    }
}

// ---------------- MFMA GEMM: feat16[t][n][:] = A @ W[t], fused el/er epilogue ----------------
// 64x128 tile/block, 4 waves; wave w owns 16-row M-tile, 8 N-tiles of 16.
// v_mfma_f32_16x16x32_f16: A lane(l): row=l&15, k=8*(l>>4)+j ; B: col=l&15, same k ;
// D: col=l&15, row=4*(l>>4)+reg.
#define APAD 136
__global__ __launch_bounds__(256) void gemm_mfma(const float* __restrict__ A,
                                                 const f16* __restrict__ Whbase,
                                                 const float* __restrict__ albase,
                                                 const float* __restrict__ arbase,
                                                 f16* __restrict__ featbase,
                                                 float* __restrict__ elbase,
                                                 float* __restrict__ erbase) {
    __shared__ f16 Asl[64 * APAD];
    __shared__ f16 Bsl[128 * APAD];
    const int et = blockIdx.y;
    const f16* Wh = Whbase + et * 16384;
    f16* feat = featbase + (size_t)et * NN * 128;
    const int row0 = blockIdx.x * 64;
    const int t = threadIdx.x;

    // stage A (64 rows x 128 k f32 -> f16), 8 float4 reads per thread
    #pragma unroll
    for (int j = 0; j < 8; ++j) {
        const int idx = t + j * 256;            // idx = row*32 + q
        const int r = idx >> 5, q = idx & 31;
        const int row = row0 + r;
        float4 v = make_float4(0.f, 0.f, 0.f, 0.f);
        if (row < NN) v = reinterpret_cast<const float4*>(A)[row * 32 + q];
        union { f16 h[4]; float2 d; } pk;
        pk.h[0] = (f16)v.x; pk.h[1] = (f16)v.y; pk.h[2] = (f16)v.z; pk.h[3] = (f16)v.w;
        *reinterpret_cast<float2*>(&Asl[r * APAD + q * 4]) = pk.d;
    }
    // stage B (Wh[col][k], 128 cols x 128 k f16 = 2048 float4s), 8 per thread
    // (round-6 bug: j<4 with k8=idx&7 left k=64..127 uninitialized -> NaN)
    #pragma unroll
    for (int j = 0; j < 8; ++j) {
        const int idx = t + j * 256;            // idx = col*16 + k16
        const int col = idx >> 4, k16 = idx & 15;
        *reinterpret_cast<float4*>(&Bsl[col * APAD + k16 * 8]) =
            *reinterpret_cast<const float4*>(Wh + col * 128 + k16 * 8);
    }
    __syncthreads();

    const int w = t >> 6, lane = t & 63;
    const int r = lane & 15, g = lane >> 4;     // r: row/col-in-tile, g: k-group
    const int mb = w * 16;
    f32x4 acc[8];
    #pragma unroll
    for (int nt = 0; nt < 8; ++nt) acc[nt] = (f32x4){0.f, 0.f, 0.f, 0.f};

    #pragma unroll
    for (int ks = 0; ks < 4; ++ks) {
        const f16x8 av = *reinterpret_cast<const f16x8*>(&Asl[(mb + r) * APAD + ks * 32 + g * 8]);
        #pragma unroll
        for (int nt = 0; nt < 8; ++nt) {
            const f16x8 bv =
                *reinterpret_cast<const f16x8*>(&Bsl[(nt * 16 + r) * APAD + ks * 32 + g * 8]);
            acc[nt] = __builtin_amdgcn_mfma_f32_16x16x32_f16(av, bv, acc[nt], 0, 0, 0);
        }
    }

    // epilogue: fp16 feat store + fused el/er
    float alv[8], arv[8];
    #pragma unroll
    for (int nt = 0; nt < 8; ++nt) {            // col = nt*16 + r ; al flat index == col
        alv[nt] = albase[et * 128 + nt * 16 + r];
        arv[nt] = arbase[et * 128 + nt * 16 + r];
    }
    #pragma unroll
    for (int p = 0; p < 4; ++p) {
        const int row = row0 + mb + g * 4 + p;
        const bool ok = row < NN;
        if (ok) {
            #pragma unroll
            for (int nt = 0; nt < 8; ++nt)
                feat[(size_t)row * 128 + nt * 16 + r] = (f16)acc[nt][p];
        }
        #pragma unroll
        for (int h = 0; h < 4; ++h) {
            float pl = fmaf(acc[2 * h][p], alv[2 * h], acc[2 * h + 1][p] * alv[2 * h + 1]);
            float pr = fmaf(acc[2 * h][p], arv[2 * h], acc[2 * h + 1][p] * arv[2 * h + 1]);
            pl += __shfl_xor(pl, 1); pl += __shfl_xor(pl, 2);
            pl += __shfl_xor(pl, 4); pl += __shfl_xor(pl, 8);
            pr += __shfl_xor(pr, 1); pr += __shfl_xor(pr, 2);
            pr += __shfl_xor(pr, 4); pr += __shfl_xor(pr, 8);
            if (ok && r == 0) {
                elbase[et * NN * HH + row * HH + h] = pl;
                erbase[et * NN * HH + row * HH + h] = pr;
            }
        }
    }
}

// ---------------- CSR build: histogram (grid.y = etype) ----------------
__global__ __launch_bounds__(256) void hist_k(const int* __restrict__ dst0,
                                              const int* __restrict__ dst1,
                                              int* __restrict__ deg) {
    const int e = blockIdx.x * 256 + threadIdx.x;
    if (e >= EE) return;
    const int t = blockIdx.y;
    const int* d = t ? dst1 : dst0;
    atomicAdd(&deg[t * NN + d[e]], 1);
}

// ---------------- multi-block exclusive scan ----------------
__global__ __launch_bounds__(256) void scan1_k(const int* __restrict__ deg,
                                               int* __restrict__ offs,
                                               int* __restrict__ blocksum) {
    const int t = blockIdx.y, b = blockIdx.x;
    const int* d = deg + t * NN;
    int* o = offs + t * (NN + 1);
    const int base = b * 2048 + threadIdx.x * 8;
    int v[8];
    int s = 0;
    #pragma unroll
    for (int j = 0; j < 8; ++j) {
        const int i = base + j;
        v[j] = (i < NN) ? d[i] : 0;
        s += v[j];
    }
    __shared__ int buf[256];
    buf[threadIdx.x] = s;
    __syncthreads();
    #pragma unroll
    for (int ofs = 1; ofs < 256; ofs <<= 1) {
        const int add = (threadIdx.x >= (unsigned)ofs) ? buf[threadIdx.x - ofs] : 0;
        __syncthreads();
        buf[threadIdx.x] += add;
        __syncthreads();
    }
    int run = buf[threadIdx.x] - s;
    #pragma unroll
    for (int j = 0; j < 8; ++j) {
        const int i = base + j;
        if (i < NN) o[i] = run;
        run += v[j];
    }
    if (threadIdx.x == 255) blocksum[t * SCAN_NB + b] = buf[255];
}

__global__ __launch_bounds__(64) void scan2_k(int* __restrict__ blocksum,
                                              int* __restrict__ offs) {
    if (threadIdx.x != 0) return;
    #pragma unroll
    for (int t = 0; t < 2; ++t) {
        int run = 0;
        for (int b = 0; b < SCAN_NB; ++b) {
            const int v = blocksum[t * SCAN_NB + b];
            blocksum[t * SCAN_NB + b] = run;
            run += v;
        }
        offs[t * (NN + 1) + NN] = run;
    }
}

__global__ __launch_bounds__(256) void scan3_k(int* __restrict__ offs,
                                               const int* __restrict__ blocksum,
                                               int* __restrict__ cursor) {
    const int t = blockIdx.y, b = blockIdx.x;
    const int boff = blocksum[t * SCAN_NB + b];
    int* o = offs + t * (NN + 1);
    int* cur = cursor + t * NN;
    const int base = b * 2048 + threadIdx.x * 8;
    #pragma unroll
    for (int j = 0; j < 8; ++j) {
        const int i = base + j;
        if (i < NN) {
            const int val = o[i] + boff;
            o[i] = val;
            cur[i] = val;
        }
    }
}

__global__ __launch_bounds__(256) void scatter_k(const int* __restrict__ src0,
                                                 const int* __restrict__ dst0,
                                                 const int* __restrict__ src1,
                                                 const int* __restrict__ dst1,
                                                 int* __restrict__ cursor,
                                                 int* __restrict__ csr_src) {
    const int e = blockIdx.x * 256 + threadIdx.x;
    if (e >= EE) return;
    const int t = blockIdx.y;
    const int* s = t ? src1 : src0;
    const int* d = t ? dst1 : dst0;
    const int pos = atomicAdd(&cursor[t * NN + d[e]], 1);
    csr_src[t * EE + pos] = s[e];
}

// ---------------- pull-mode fused softmax+aggregate+bias(+relu): one wave per node ----------------
__global__ __launch_bounds__(256) void pull_agg_k(const int* __restrict__ csr_src,
                                                  const int* __restrict__ offs,
                                                  const float* __restrict__ el,
                                                  const float* __restrict__ er,
                                                  const f16* __restrict__ feat,
                                                  const float* __restrict__ b0,
                                                  const float* __restrict__ b1,
                                                  float* __restrict__ out, int relu) {
    const int wave = (blockIdx.x * 256 + threadIdx.x) >> 6;
    const int lane = threadIdx.x & 63;
    if (wave >= NN) return;
    const int n = wave;
    const int c0 = lane * 2;
    const int h = c0 >> 5;
    float a0 = 0.f, a1 = 0.f;
    #pragma unroll
    for (int t = 0; t < 2; ++t) {
        const int* so = offs + t * (NN + 1);
        const int e0 = so[n], e1 = so[n + 1];
        const float erh = er[t * NN * HH + n * HH + h];
        const int* cs = csr_src + t * EE;
        const f16* ft = feat + (size_t)t * NN * 128;
        const float* elt = el + t * NN * HH;
        float sA = 0.f, x0A = 0.f, x1A = 0.f;
        float sB = 0.f, x0B = 0.f, x1B = 0.f;
        float sC = 0.f, x0C = 0.f, x1C = 0.f;
        float sD = 0.f, x0D = 0.f, x1D = 0.f;
        int e = e0;
        for (; e + 3 < e1; e += 4) {
            const int sa = cs[e], sb = cs[e + 1], sc = cs[e + 2], sd = cs[e + 3];
            float va = elt[sa * HH + h] + erh;
            float vb = elt[sb * HH + h] + erh;
            float vc = elt[sc * HH + h] + erh;
            float vd = elt[sd * HH + h] + erh;
            const f16x2 fa = *reinterpret_cast<const f16x2*>(ft + (size_t)sa * 128 + c0);
            const f16x2 fb = *reinterpret_cast<const f16x2*>(ft + (size_t)sb * 128 + c0);
            const f16x2 fc = *reinterpret_cast<const f16x2*>(ft + (size_t)sc * 128 + c0);
            const f16x2 fd = *reinterpret_cast<const f16x2*>(ft + (size_t)sd * 128 + c0);
            va = (va >= 0.f) ? va : va * SLOPE;
            vb = (vb >= 0.f) ? vb : vb * SLOPE;
            vc = (vc >= 0.f) ? vc : vc * SLOPE;
            vd = (vd >= 0.f) ? vd : vd * SLOPE;
            const float ea = __expf(va), eb = __expf(vb);
            const float ec = __expf(vc), ed = __expf(vd);
            sA += ea; x0A = fmaf(ea, (float)fa.x, x0A); x1A = fmaf(ea, (float)fa.y, x1A);
            sB += eb; x0B = fmaf(eb, (float)fb.x, x0B); x1B = fmaf(eb, (float)fb.y, x1B);
            sC += ec; x0C = fmaf(ec, (float)fc.x, x0C); x1C = fmaf(ec, (float)fc.y, x1C);
            sD += ed; x0D = fmaf(ed, (float)fd.x, x0D); x1D = fmaf(ed, (float)fd.y, x1D);
        }
        for (; e < e1; ++e) {
            const int sa = cs[e];
            float va = elt[sa * HH + h] + erh;
            va = (va >= 0.f) ? va : va * SLOPE;
            const float ea = __expf(va);
            const f16x2 fa = *reinterpret_cast<const f16x2*>(ft + (size_t)sa * 128 + c0);
            sA += ea; x0A = fmaf(ea, (float)fa.x, x0A); x1A = fmaf(ea, (float)fa.y, x1A);
        }
        const float s = (sA + sB) + (sC + sD);
        const float x0 = (x0A + x0B) + (x0C + x0D);
        const float x1 = (x1A + x1B) + (x1C + x1D);
        const float inv = (s > 0.f) ? 1.f / s : 0.f;
        a0 = fmaf(x0, inv, a0);
        a1 = fmaf(x1, inv, a1);
    }
    a0 += b0[c0] + b1[c0];
    a1 += b0[c0 + 1] + b1[c0 + 1];
    if (relu) { a0 = fmaxf(a0, 0.f); a1 = fmaxf(a1, 0.f); }
    *reinterpret_cast<float2*>(out + (size_t)n * 128 + c0) = make_float2(a0, a1);
}

// ---------------- final linear ----------------
__global__ __launch_bounds__(256) void out_gemm_k(const float* __restrict__ A,
                                                  const float* __restrict__ W,
                                                  const float* __restrict__ bout,
                                                  float* __restrict__ out) {
    __shared__ float At[16][132];
    const int row0 = blockIdx.x * 16;
    const int t = threadIdx.x;
    for (int i = t; i < 16 * 32; i += 256) {
        const int r = i >> 5, c4 = i & 31;
        *reinterpret_cast<float4*>(&At[r][c4 * 4]) =
            reinterpret_cast<const float4*>(A)[(row0 + r) * 32 + c4];
    }
    __syncthreads();
    const int r = t >> 4, c = t & 15;
    float accv = 0.f;
    #pragma unroll 8
    for (int k = 0; k < 128; ++k) accv = fmaf(At[r][k], W[k * 16 + c], accv);
    out[(row0 + r) * 16 + c] = accv + bout[c];
}

extern "C" void kernel_launch(void* const* d_in, const int* in_sizes, int n_in,
                              void* d_out, int out_size, void* d_ws, size_t ws_size,
                              hipStream_t stream) {
    (void)in_sizes; (void)n_in; (void)out_size; (void)ws_size;
    const float* x = (const float*)d_in[0];
    const int* src0 = (const int*)d_in[1];
    const int* dst0 = (const int*)d_in[2];
    const int* src1 = (const int*)d_in[3];
    const int* dst1 = (const int*)d_in[4];
    const float* W[3]  = {(const float*)d_in[5], (const float*)d_in[9],  (const float*)d_in[13]};
    const float* al[3] = {(const float*)d_in[6], (const float*)d_in[10], (const float*)d_in[14]};
    const float* ar[3] = {(const float*)d_in[7], (const float*)d_in[11], (const float*)d_in[15]};
    const float* bb[3] = {(const float*)d_in[8], (const float*)d_in[12], (const float*)d_in[16]};
    const float* Wout = (const float*)d_in[17];
    const float* bout = (const float*)d_in[18];
    float* outp = (float*)d_out;

    char* pb = (char*)d_ws;
    f16* feat   = (f16*)pb;    pb += (size_t)2 * NN * 128 * 2;   // [2][NN][128] fp16
    float* hbuf = (float*)pb;  pb += (size_t)NN * 128 * 4;
    float* el   = (float*)pb;  pb += (size_t)2 * NN * HH * 4;
    float* er   = (float*)pb;  pb += (size_t)2 * NN * HH * 4;
    int* deg    = (int*)pb;    pb += (size_t)2 * NN * 4;
    int* cursor = (int*)pb;    pb += (size_t)2 * NN * 4;
    int* offs   = (int*)pb;    pb += (size_t)2 * (NN + 1) * 4;
    int* bsum   = (int*)pb;    pb += (size_t)2 * SCAN_NB * 4;
    f16* Wh     = (f16*)pb;    pb += (size_t)3 * 2 * 128 * 128 * 2;
    int* csr    = (int*)pb;    pb += (size_t)2 * EE * 4;

    // ---- CSR build + weight pre-convert (once per call) ----
    zero_k<<<(2 * NN / 4 + 255) / 256, 256, 0, stream>>>((int4*)deg, 2 * NN / 4);
    hist_k<<<dim3((EE + 255) / 256, 2), 256, 0, stream>>>(dst0, dst1, deg);
    scan1_k<<<dim3(SCAN_NB, 2), 256, 0, stream>>>(deg, offs, bsum);
    scan2_k<<<1, 64, 0, stream>>>(bsum, offs);
    scan3_k<<<dim3(SCAN_NB, 2), 256, 0, stream>>>(offs, bsum, cursor);
    scatter_k<<<dim3((EE + 255) / 256, 2), 256, 0, stream>>>(src0, dst0, src1, dst1, cursor, csr);
    for (int l = 0; l < 3; ++l)
        wconv_k<<<dim3(8, 2), 256, 0, stream>>>(W[l], Wh + l * 2 * 16384);

    // ---- 3 GAT layers ----
    const float* hin = x;
    for (int l = 0; l < 3; ++l) {
        gemm_mfma<<<dim3((NN + 63) / 64, 2), 256, 0, stream>>>(hin, Wh + l * 2 * 16384,
                                                               al[l], ar[l], feat, el, er);
        pull_agg_k<<<NN / 4, 256, 0, stream>>>(csr, offs, el, er, feat,
                                               bb[l], bb[l] + 128, hbuf, (l < 2) ? 1 : 0);
        hin = hbuf;
    }
    out_gemm_k<<<NN / 16, 256, 0, stream>>>(hbuf, Wout, bout, outp);
}

// Round 8
// 266.314 us; speedup vs baseline: 6.3799x; 1.0193x over previous
//
#include <hip/hip_runtime.h>

#define NN 30000
#define EE 300000
#define HH 4
#define SLOPE 0.2f
#define SCAN_NB 15        // ceil(30000 / 2048)

typedef _Float16 f16;
struct f16x2 { f16 x, y; };
typedef f16 f16x8 __attribute__((ext_vector_type(8)));
typedef float f32x4 __attribute__((ext_vector_type(4)));

// ---------------- zero deg (rocclr fill kernel costs 43us; this is ~2us) ----------------
__global__ __launch_bounds__(256) void zero_k(int4* __restrict__ p, int n4) {
    const int i = blockIdx.x * 256 + threadIdx.x;
    if (i < n4) p[i] = make_int4(0, 0, 0, 0);
}

// ---------------- x -> f16 (once per call) ----------------
__global__ __launch_bounds__(256) void xconv_k(const float* __restrict__ x,
                                               f16* __restrict__ xh) {
    const int i = blockIdx.x * 256 + threadIdx.x;   // i < NN*128/8 exactly
    const float4 a = reinterpret_cast<const float4*>(x)[i * 2];
    const float4 b = reinterpret_cast<const float4*>(x)[i * 2 + 1];
    union { f16 h[8]; float4 f4; } pk;
    pk.h[0] = (f16)a.x; pk.h[1] = (f16)a.y; pk.h[2] = (f16)a.z; pk.h[3] = (f16)a.w;
    pk.h[4] = (f16)b.x; pk.h[5] = (f16)b.y; pk.h[6] = (f16)b.z; pk.h[7] = (f16)b.w;
    reinterpret_cast<float4*>(xh)[i] = pk.f4;
}

// ---------------- W pre-convert for all 3 layers: Wh[l][t][col][k] = (f16) W[l][t][k][col] ----------------
__global__ __launch_bounds__(256) void wconv3_k(const float* __restrict__ W0,
                                                const float* __restrict__ W1,
                                                const float* __restrict__ W2,
                                                f16* __restrict__ Wh) {
    const int l = blockIdx.z, t = blockIdx.y;
    const float* W = (l == 0) ? W0 : ((l == 1) ? W1 : W2);
    f16* Whl = Wh + (size_t)l * 2 * 16384;
    const int i0 = blockIdx.x * 2048;
    #pragma unroll
    for (int j = 0; j < 8; ++j) {
        const int i = i0 + threadIdx.x + j * 256;     // i = k*128 + col (coalesced read)
        const int k = i >> 7, col = i & 127;
        Whl[t * 16384 + col * 128 + k] = (f16)W[t * 16384 + i];
    }
}

// ---------------- MFMA GEMM: feat16[t][n][:] = Ah @ W[t], fused el/er epilogue ----------------
// 64x128 tile/block, 4 waves; wave w owns 16-row M-tile, 8 N-tiles of 16.
// v_mfma_f32_16x16x32_f16: A lane(l): row=l&15, k=8*(l>>4)+j ; B: col=l&15, same k ;
// D: col=l&15, row=4*(l>>4)+reg.
#define APAD 136
__global__ __launch_bounds__(256) void gemm_mfma(const f16* __restrict__ Ah,
                                                 const f16* __restrict__ Whbase,
                                                 const float* __restrict__ albase,
                                                 const float* __restrict__ arbase,
                                                 f16* __restrict__ featbase,
                                                 float* __restrict__ elbase,
                                                 float* __restrict__ erbase) {
    __shared__ f16 Asl[64 * APAD];
    __shared__ f16 Bsl[128 * APAD];
    const int et = blockIdx.y;
    const f16* Wh = Whbase + et * 16384;
    f16* feat = featbase + (size_t)et * NN * 128;
    const int row0 = blockIdx.x * 64;
    const int t = threadIdx.x;

    // stage A (64 rows x 128 k f16 = 1024 float4s), 4 per thread, straight copy
    #pragma unroll
    for (int j = 0; j < 4; ++j) {
        const int idx = t + j * 256;            // idx = row*16 + q
        const int r = idx >> 4, q = idx & 15;
        const int row = row0 + r;
        float4 v = make_float4(0.f, 0.f, 0.f, 0.f);
        if (row < NN) v = reinterpret_cast<const float4*>(Ah + (size_t)row * 128)[q];
        *reinterpret_cast<float4*>(&Asl[r * APAD + q * 8]) = v;
    }
    // stage B (Wh[col][k], 128 cols x 128 k f16 = 2048 float4s), 8 per thread
    #pragma unroll
    for (int j = 0; j < 8; ++j) {
        const int idx = t + j * 256;            // idx = col*16 + k16
        const int col = idx >> 4, k16 = idx & 15;
        *reinterpret_cast<float4*>(&Bsl[col * APAD + k16 * 8]) =
            *reinterpret_cast<const float4*>(Wh + col * 128 + k16 * 8);
    }
    __syncthreads();

    const int w = t >> 6, lane = t & 63;
    const int r = lane & 15, g = lane >> 4;     // r: row/col-in-tile, g: k-group
    const int mb = w * 16;
    f32x4 acc[8];
    #pragma unroll
    for (int nt = 0; nt < 8; ++nt) acc[nt] = (f32x4){0.f, 0.f, 0.f, 0.f};

    #pragma unroll
    for (int ks = 0; ks < 4; ++ks) {
        const f16x8 av = *reinterpret_cast<const f16x8*>(&Asl[(mb + r) * APAD + ks * 32 + g * 8]);
        #pragma unroll
        for (int nt = 0; nt < 8; ++nt) {
            const f16x8 bv =
                *reinterpret_cast<const f16x8*>(&Bsl[(nt * 16 + r) * APAD + ks * 32 + g * 8]);
            acc[nt] = __builtin_amdgcn_mfma_f32_16x16x32_f16(av, bv, acc[nt], 0, 0, 0);
        }
    }

    // epilogue: fp16 feat store + fused el/er
    float alv[8], arv[8];
    #pragma unroll
    for (int nt = 0; nt < 8; ++nt) {            // col = nt*16 + r ; al flat index == col
        alv[nt] = albase[et * 128 + nt * 16 + r];
        arv[nt] = arbase[et * 128 + nt * 16 + r];
    }
    #pragma unroll
    for (int p = 0; p < 4; ++p) {
        const int row = row0 + mb + g * 4 + p;
        const bool ok = row < NN;
        if (ok) {
            #pragma unroll
            for (int nt = 0; nt < 8; ++nt)
                feat[(size_t)row * 128 + nt * 16 + r] = (f16)acc[nt][p];
        }
        #pragma unroll
        for (int h = 0; h < 4; ++h) {
            float pl = fmaf(acc[2 * h][p], alv[2 * h], acc[2 * h + 1][p] * alv[2 * h + 1]);
            float pr = fmaf(acc[2 * h][p], arv[2 * h], acc[2 * h + 1][p] * arv[2 * h + 1]);
            pl += __shfl_xor(pl, 1); pl += __shfl_xor(pl, 2);
            pl += __shfl_xor(pl, 4); pl += __shfl_xor(pl, 8);
            pr += __shfl_xor(pr, 1); pr += __shfl_xor(pr, 2);
            pr += __shfl_xor(pr, 4); pr += __shfl_xor(pr, 8);
            if (ok && r == 0) {
                elbase[et * NN * HH + row * HH + h] = pl;
                erbase[et * NN * HH + row * HH + h] = pr;
            }
        }
    }
}

// ---------------- CSR build: histogram (grid.y = etype) ----------------
__global__ __launch_bounds__(256) void hist_k(const int* __restrict__ dst0,
                                              const int* __restrict__ dst1,
                                              int* __restrict__ deg) {
    const int e = blockIdx.x * 256 + threadIdx.x;
    if (e >= EE) return;
    const int t = blockIdx.y;
    const int* d = t ? dst1 : dst0;
    atomicAdd(&deg[t * NN + d[e]], 1);
}

// ---------------- multi-block exclusive scan ----------------
__global__ __launch_bounds__(256) void scan1_k(const int* __restrict__ deg,
                                               int* __restrict__ offs,
                                               int* __restrict__ blocksum) {
    const int t = blockIdx.y, b = blockIdx.x;
    const int* d = deg + t * NN;
    int* o = offs + t * (NN + 1);
    const int base = b * 2048 + threadIdx.x * 8;
    int v[8];
    int s = 0;
    #pragma unroll
    for (int j = 0; j < 8; ++j) {
        const int i = base + j;
        v[j] = (i < NN) ? d[i] : 0;
        s += v[j];
    }
    __shared__ int buf[256];
    buf[threadIdx.x] = s;
    __syncthreads();
    #pragma unroll
    for (int ofs = 1; ofs < 256; ofs <<= 1) {
        const int add = (threadIdx.x >= (unsigned)ofs) ? buf[threadIdx.x - ofs] : 0;
        __syncthreads();
        buf[threadIdx.x] += add;
        __syncthreads();
    }
    int run = buf[threadIdx.x] - s;
    #pragma unroll
    for (int j = 0; j < 8; ++j) {
        const int i = base + j;
        if (i < NN) o[i] = run;
        run += v[j];
    }
    if (threadIdx.x == 255) blocksum[t * SCAN_NB + b] = buf[255];
}

__global__ __launch_bounds__(64) void scan2_k(int* __restrict__ blocksum,
                                              int* __restrict__ offs) {
    if (threadIdx.x != 0) return;
    #pragma unroll
    for (int t = 0; t < 2; ++t) {
        int run = 0;
        for (int b = 0; b < SCAN_NB; ++b) {
            const int v = blocksum[t * SCAN_NB + b];
            blocksum[t * SCAN_NB + b] = run;
            run += v;
        }
        offs[t * (NN + 1) + NN] = run;
    }
}

__global__ __launch_bounds__(256) void scan3_k(int* __restrict__ offs,
                                               const int* __restrict__ blocksum,
                                               int* __restrict__ cursor) {
    const int t = blockIdx.y, b = blockIdx.x;
    const int boff = blocksum[t * SCAN_NB + b];
    int* o = offs + t * (NN + 1);
    int* cur = cursor + t * NN;
    const int base = b * 2048 + threadIdx.x * 8;
    #pragma unroll
    for (int j = 0; j < 8; ++j) {
        const int i = base + j;
        if (i < NN) {
            const int val = o[i] + boff;
            o[i] = val;
            cur[i] = val;
        }
    }
}

__global__ __launch_bounds__(256) void scatter_k(const int* __restrict__ src0,
                                                 const int* __restrict__ dst0,
                                                 const int* __restrict__ src1,
                                                 const int* __restrict__ dst1,
                                                 int* __restrict__ cursor,
                                                 int* __restrict__ csr_src) {
    const int e = blockIdx.x * 256 + threadIdx.x;
    if (e >= EE) return;
    const int t = blockIdx.y;
    const int* s = t ? src1 : src0;
    const int* d = t ? dst1 : dst0;
    const int pos = atomicAdd(&cursor[t * NN + d[e]], 1);
    csr_src[t * EE + pos] = s[e];
}

// ---------------- pull-mode fused softmax+aggregate+bias(+relu) ----------------
// one wave per (node, etype): block = 4 waves = 2 nodes x 2 etypes; LDS combine.
__global__ __launch_bounds__(256) void pull_agg2_k(const int* __restrict__ csr_src,
                                                   const int* __restrict__ offs,
                                                   const float* __restrict__ el,
                                                   const float* __restrict__ er,
                                                   const f16* __restrict__ feat,
                                                   const float* __restrict__ b0,
                                                   const float* __restrict__ b1,
                                                   f16* __restrict__ out, int relu) {
    __shared__ float xb[2][2][128];             // [node-parity][etype][col]
    const int w = threadIdx.x >> 6, lane = threadIdx.x & 63;
    const int p = w >> 1, t = w & 1;
    const int n = blockIdx.x * 2 + p;           // NN even: always valid
    const int c0 = lane * 2;
    const int h = c0 >> 5;

    const int* so = offs + t * (NN + 1);
    const int e0 = so[n], e1 = so[n + 1];
    const float erh = er[t * NN * HH + n * HH + h];
    const int* cs = csr_src + t * EE;
    const f16* ft = feat + (size_t)t * NN * 128;
    const float* elt = el + t * NN * HH;
    float sA = 0.f, x0A = 0.f, x1A = 0.f;
    float sB = 0.f, x0B = 0.f, x1B = 0.f;
    float sC = 0.f, x0C = 0.f, x1C = 0.f;
    float sD = 0.f, x0D = 0.f, x1D = 0.f;
    int e = e0;
    for (; e + 3 < e1; e += 4) {
        const int sa = cs[e], sb = cs[e + 1], sc = cs[e + 2], sd = cs[e + 3];
        float va = elt[sa * HH + h] + erh;
        float vb = elt[sb * HH + h] + erh;
        float vc = elt[sc * HH + h] + erh;
        float vd = elt[sd * HH + h] + erh;
        const f16x2 fa = *reinterpret_cast<const f16x2*>(ft + (size_t)sa * 128 + c0);
        const f16x2 fb = *reinterpret_cast<const f16x2*>(ft + (size_t)sb * 128 + c0);
        const f16x2 fc = *reinterpret_cast<const f16x2*>(ft + (size_t)sc * 128 + c0);
        const f16x2 fd = *reinterpret_cast<const f16x2*>(ft + (size_t)sd * 128 + c0);
        va = (va >= 0.f) ? va : va * SLOPE;
        vb = (vb >= 0.f) ? vb : vb * SLOPE;
        vc = (vc >= 0.f) ? vc : vc * SLOPE;
        vd = (vd >= 0.f) ? vd : vd * SLOPE;
        const float ea = __expf(va), eb = __expf(vb);
        const float ec = __expf(vc), ed = __expf(vd);
        sA += ea; x0A = fmaf(ea, (float)fa.x, x0A); x1A = fmaf(ea, (float)fa.y, x1A);
        sB += eb; x0B = fmaf(eb, (float)fb.x, x0B); x1B = fmaf(eb, (float)fb.y, x1B);
        sC += ec; x0C = fmaf(ec, (float)fc.x, x0C); x1C = fmaf(ec, (float)fc.y, x1C);
        sD += ed; x0D = fmaf(ed, (float)fd.x, x0D); x1D = fmaf(ed, (float)fd.y, x1D);
    }
    for (; e < e1; ++e) {
        const int sa = cs[e];
        float va = elt[sa * HH + h] + erh;
        va = (va >= 0.f) ? va : va * SLOPE;
        const float ea = __expf(va);
        const f16x2 fa = *reinterpret_cast<const f16x2*>(ft + (size_t)sa * 128 + c0);
        sA += ea; x0A = fmaf(ea, (float)fa.x, x0A); x1A = fmaf(ea, (float)fa.y, x1A);
    }
    const float s = (sA + sB) + (sC + sD);
    const float inv = (s > 0.f) ? 1.f / s : 0.f;    // isolated node -> 0, matches ref
    xb[p][t][c0]     = ((x0A + x0B) + (x0C + x0D)) * inv;
    xb[p][t][c0 + 1] = ((x1A + x1B) + (x1C + x1D)) * inv;
    __syncthreads();
    if (t == 0) {
        float a0 = xb[p][0][c0] + xb[p][1][c0] + b0[c0] + b1[c0];
        float a1 = xb[p][0][c0 + 1] + xb[p][1][c0 + 1] + b0[c0 + 1] + b1[c0 + 1];
        if (relu) { a0 = fmaxf(a0, 0.f); a1 = fmaxf(a1, 0.f); }
        f16x2 o; o.x = (f16)a0; o.y = (f16)a1;
        *reinterpret_cast<f16x2*>(out + (size_t)n * 128 + c0) = o;
    }
}

// ---------------- final linear (f16 input) ----------------
__global__ __launch_bounds__(256) void out_gemm_k(const f16* __restrict__ A,
                                                  const float* __restrict__ W,
                                                  const float* __restrict__ bout,
                                                  float* __restrict__ out) {
    __shared__ float At[16][132];
    const int row0 = blockIdx.x * 16;   // NN % 16 == 0
    const int t = threadIdx.x;
    {
        const int r = t >> 4, c8 = t & 15;    // 256 threads cover 16 rows x 16 groups of 8
        const f16x8 v = *reinterpret_cast<const f16x8*>(A + (size_t)(row0 + r) * 128 + c8 * 8);
        #pragma unroll
        for (int j = 0; j < 8; ++j) At[r][c8 * 8 + j] = (float)v[j];
    }
    __syncthreads();
    const int r = t >> 4, c = t & 15;
    float accv = 0.f;
    #pragma unroll 8
    for (int k = 0; k < 128; ++k) accv = fmaf(At[r][k], W[k * 16 + c], accv);
    out[(row0 + r) * 16 + c] = accv + bout[c];
}

extern "C" void kernel_launch(void* const* d_in, const int* in_sizes, int n_in,
                              void* d_out, int out_size, void* d_ws, size_t ws_size,
                              hipStream_t stream) {
    (void)in_sizes; (void)n_in; (void)out_size; (void)ws_size;
    const float* x = (const float*)d_in[0];
    const int* src0 = (const int*)d_in[1];
    const int* dst0 = (const int*)d_in[2];
    const int* src1 = (const int*)d_in[3];
    const int* dst1 = (const int*)d_in[4];
    const float* W[3]  = {(const float*)d_in[5], (const float*)d_in[9],  (const float*)d_in[13]};
    const float* al[3] = {(const float*)d_in[6], (const float*)d_in[10], (const float*)d_in[14]};
    const float* ar[3] = {(const float*)d_in[7], (const float*)d_in[11], (const float*)d_in[15]};
    const float* bb[3] = {(const float*)d_in[8], (const float*)d_in[12], (const float*)d_in[16]};
    const float* Wout = (const float*)d_in[17];
    const float* bout = (const float*)d_in[18];
    float* outp = (float*)d_out;

    char* pb = (char*)d_ws;
    f16* feat   = (f16*)pb;    pb += (size_t)2 * NN * 128 * 2;   // [2][NN][128] fp16
    f16* xh     = (f16*)pb;    pb += (size_t)NN * 128 * 2;
    f16* hbuf   = (f16*)pb;    pb += (size_t)NN * 128 * 2;
    float* el   = (float*)pb;  pb += (size_t)2 * NN * HH * 4;
    float* er   = (float*)pb;  pb += (size_t)2 * NN * HH * 4;
    int* deg    = (int*)pb;    pb += (size_t)2 * NN * 4;
    int* cursor = (int*)pb;    pb += (size_t)2 * NN * 4;
    int* offs   = (int*)pb;    pb += (size_t)2 * (NN + 1) * 4;
    int* bsum   = (int*)pb;    pb += (size_t)2 * SCAN_NB * 4;
    f16* Wh     = (f16*)pb;    pb += (size_t)3 * 2 * 128 * 128 * 2;
    int* csr    = (int*)pb;    pb += (size_t)2 * EE * 4;

    // ---- CSR build + precompute (once per call) ----
    zero_k<<<(2 * NN / 4 + 255) / 256, 256, 0, stream>>>((int4*)deg, 2 * NN / 4);
    hist_k<<<dim3((EE + 255) / 256, 2), 256, 0, stream>>>(dst0, dst1, deg);
    scan1_k<<<dim3(SCAN_NB, 2), 256, 0, stream>>>(deg, offs, bsum);
    scan2_k<<<1, 64, 0, stream>>>(bsum, offs);
    scan3_k<<<dim3(SCAN_NB, 2), 256, 0, stream>>>(offs, bsum, cursor);
    scatter_k<<<dim3((EE + 255) / 256, 2), 256, 0, stream>>>(src0, dst0, src1, dst1, cursor, csr);
    wconv3_k<<<dim3(8, 2, 3), 256, 0, stream>>>(W[0], W[1], W[2], Wh);
    xconv_k<<<NN * 128 / 8 / 256, 256, 0, stream>>>(x, xh);

    // ---- 3 GAT layers ----
    const f16* hin = xh;
    for (int l = 0; l < 3; ++l) {
        gemm_mfma<<<dim3((NN + 63) / 64, 2), 256, 0, stream>>>(hin, Wh + l * 2 * 16384,
                                                               al[l], ar[l], feat, el, er);
        pull_agg2_k<<<NN / 2, 256, 0, stream>>>(csr, offs, el, er, feat,
                                                bb[l], bb[l] + 128, hbuf, (l < 2) ? 1 : 0);
        hin = hbuf;
    }
    out_gemm_k<<<NN / 16, 256, 0, stream>>>(hbuf, Wout, bout, outp);
}